// Round 9
// baseline (384.471 us; speedup 1.0000x reference)
//
#include <hip/hip_runtime.h>

#define D 128
typedef unsigned short u16;
constexpr int NW = 30000;
constexpr int NT = 2000;
constexpr int NDOC = 20000;
constexpr int NSLOT = NW + NT + NT + NDOC + NDOC;   // 74000 destination slots
constexpr int SEG_WW = 0;
constexpr int SEG_WT = NW;                 // 30000
constexpr int SEG_TT = NW + NT;            // 32000
constexpr int SEG_WD = NW + 2 * NT;        // 34000
constexpr int SEG_TD = NW + 2 * NT + NDOC; // 54000
constexpr int NP2 = NT + NT + NDOC + NDOC; // 44000 phase-2 slots

constexpr int BWS = 128;                    // slots per bucket (pow2: slot>>7)
constexpr int NBKT = (NSLOT + BWS - 1) / BWS;  // 579
constexpr int EPB = 2048;                   // edges per partition block (grid ~704)

struct RelDesc { const int* src; const int* dst; const float* w; int e0; int seg; };
struct Rels { RelDesc r[5]; };

__device__ __forceinline__ void resolve_rel(const Rels& R, int e,
    const int*& srcp, const int*& dstp, const float*& wp, int& le, int& seg)
{
    int k;
    if (e < R.r[1].e0) k = 0;
    else if (e < R.r[2].e0) k = 1;
    else if (e < R.r[3].e0) k = 2;
    else if (e < R.r[4].e0) k = 3;
    else k = 4;
    srcp = R.r[k].src; dstp = R.r[k].dst; wp = R.r[k].w;
    le = e - R.r[k].e0; seg = R.r[k].seg;
}

__device__ __forceinline__ float b2f(u16 h)
{
    return __uint_as_float(((unsigned)h) << 16);
}
__device__ __forceinline__ u16 f2b(float f)   // round-to-nearest-even
{
    unsigned u = __float_as_uint(f);
    return (u16)((u + 0x7FFF + ((u >> 16) & 1)) >> 16);
}

// ---------------------------------------------------------------------------
// fp32 -> bf16 table conversion (feat_word): 4 elements per thread.
// ---------------------------------------------------------------------------
__global__ __launch_bounds__(256) void f2b_kernel(
    const float* __restrict__ X, u16* __restrict__ Y, int n4)
{
    int i = blockIdx.x * 256 + threadIdx.x;
    if (i >= n4) return;
    float4 v = ((const float4*)X)[i];
    ushort4 o;
    o.x = f2b(v.x); o.y = f2b(v.y); o.z = f2b(v.z); o.w = f2b(v.w);
    ((ushort4*)Y)[i] = o;
}

// ---------------------------------------------------------------------------
// Analytic bucket capacities + prefix scan -> bucket_base/cursor (PADDED
// coordinates, used only for edataA which is sized for them). Also zeroes
// the global compaction cursor used by bucket_csr.
// cap_k = 1.5 * expected_edges(bucket k) + 128 (>=18 sigma margin; dst are
// uniform-random so binomial tails are astronomically safe).
// ---------------------------------------------------------------------------
__global__ __launch_bounds__(256) void cap_scan_kernel(
    float m_ww, float m_wt, float m_tt, float m_wd, float m_td,
    int* __restrict__ bucket_base, int* __restrict__ bucket_cursor,
    int* __restrict__ gcur)
{
    __shared__ int chs[256];
    __shared__ int vals[256 * 3];
    int tid = threadIdx.x;
    if (tid == 0) *gcur = 0;
    int s = 0;
    for (int j = 0; j < 3; ++j) {
        int k = tid * 3 + j;
        int c = 0;
        if (k < NBKT) {
            int a = k * BWS, b = min(a + BWS, NSLOT);
            auto ov = [&](int lo, int hi) {
                return (float)max(0, min(b, hi) - max(a, lo));
            };
            float ex = ov(SEG_WW, SEG_WT) * m_ww + ov(SEG_WT, SEG_TT) * m_wt
                     + ov(SEG_TT, SEG_WD) * m_tt + ov(SEG_WD, SEG_TD) * m_wd
                     + ov(SEG_TD, NSLOT) * m_td;
            c = (int)(ex * 1.5f) + 128;
        }
        vals[tid * 3 + j] = c;
        s += c;
    }
    chs[tid] = s;
    __syncthreads();
    for (int off = 1; off < 256; off <<= 1) {
        int t = (tid >= off) ? chs[tid - off] : 0;
        __syncthreads();
        chs[tid] += t;
        __syncthreads();
    }
    int run = (tid == 0) ? 0 : chs[tid - 1];
    for (int j = 0; j < 3; ++j) {
        int k = tid * 3 + j;
        if (k < NBKT) {
            bucket_base[k] = run;
            bucket_cursor[k] = run;
            run += vals[tid * 3 + j];
        }
    }
}

// ---------------------------------------------------------------------------
// A3: partition edges into capacity-padded bucket regions of edataA. One
// global atomic per (block,bucket); writes are contiguous chunks.
// Entry: x = src | (dloc<<15), y = w bits.
// ---------------------------------------------------------------------------
__global__ __launch_bounds__(256) void partition_kernel(
    Rels R, int Etot, int* __restrict__ bucket_cursor, int2* __restrict__ edataA)
{
    __shared__ int hist[NBKT];
    __shared__ int baseL[NBKT];
    __shared__ u16 bkt[EPB];
    __shared__ unsigned char dl[EPB];
    int tid = threadIdx.x;
    for (int i = tid; i < NBKT; i += 256) hist[i] = 0;
    __syncthreads();
    int base_e = blockIdx.x * EPB;
    for (int r = 0; r < EPB / 256; ++r) {
        int idx = r * 256 + tid;
        int e = base_e + idx;
        if (e < Etot) {
            const int *srcp, *dstp; const float* wp; int le, seg;
            resolve_rel(R, e, srcp, dstp, wp, le, seg);
            int g = seg + dstp[le];
            bkt[idx] = (u16)(g >> 7);
            dl[idx] = (unsigned char)(g & 127);
            atomicAdd(&hist[g >> 7], 1);
        } else {
            bkt[idx] = 0xFFFF;
        }
    }
    __syncthreads();
    for (int i = tid; i < NBKT; i += 256)
        baseL[i] = hist[i] ? atomicAdd(&bucket_cursor[i], hist[i]) : 0;
    __syncthreads();
    for (int i = tid; i < NBKT; i += 256) hist[i] = 0;
    __syncthreads();
    for (int r = 0; r < EPB / 256; ++r) {
        int idx = r * 256 + tid;
        int e = base_e + idx;
        if (e < Etot) {
            const int *srcp, *dstp; const float* wp; int le, seg;
            resolve_rel(R, e, srcp, dstp, wp, le, seg);
            int b = bkt[idx];
            int rk = atomicAdd(&hist[b], 1);
            edataA[baseL[b] + rk] =
                make_int2(srcp[le] | ((int)dl[idx] << 15), __float_as_int(wp[le]));
        }
    }
}

// ---------------------------------------------------------------------------
// B: one block (1024 threads) per bucket. LDS histogram over 128 slots ->
// scan -> COMPACT: claim nk contiguous entries of edataB via one global
// atomic (gcur), so edataB indices stay < E_total even though edataA uses
// padded coordinates. Emits offsets + degf + edges in CSR order.
// ---------------------------------------------------------------------------
__global__ __launch_bounds__(1024) void bucket_csr_kernel(
    const int* __restrict__ bucket_base, const int* __restrict__ bucket_cursor,
    const int2* __restrict__ edataA, int2* __restrict__ edataB,
    int* __restrict__ offsets, float* __restrict__ degf, int* __restrict__ gcur)
{
    int k = blockIdx.x;
    int bstart = bucket_base[k], bend = bucket_cursor[k];
    int nk = bend - bstart;
    __shared__ int h2[BWS];
    __shared__ int exc[BWS];
    __shared__ int cbase;
    int tid = threadIdx.x;
    if (tid == 0) cbase = atomicAdd(gcur, nk);   // compacted output base
    if (tid < BWS) h2[tid] = 0;
    __syncthreads();
    for (int i = bstart + tid; i < bend; i += 1024) {
        int dloc = (edataA[i].x >> 15) & 127;
        atomicAdd(&h2[dloc], 1);
    }
    __syncthreads();
    if (tid < BWS) exc[tid] = h2[tid];
    __syncthreads();
    for (int off = 1; off < BWS; off <<= 1) {
        int t = 0;
        if (tid < BWS && tid >= off) t = exc[tid - off];
        __syncthreads();
        if (tid < BWS) exc[tid] += t;
        __syncthreads();
    }
    if (tid < BWS) exc[tid] -= h2[tid];   // exclusive
    __syncthreads();
    int slot0 = k * BWS;
    if (tid < BWS && slot0 + tid < NSLOT) {
        offsets[slot0 + tid] = cbase + exc[tid];
        degf[slot0 + tid] = (float)h2[tid];
    }
    __syncthreads();
    if (tid < BWS) h2[tid] = 0;
    __syncthreads();
    for (int i = bstart + tid; i < bend; i += 1024) {
        int2 e = edataA[i];
        int dloc = (e.x >> 15) & 127;
        int rk = atomicAdd(&h2[dloc], 1);
        edataB[cbase + exc[dloc] + rk] = e;
    }
}

// ---------------------------------------------------------------------------
// Segmented reduction core (one wave per dst slot). Gather table bf16,
// accumulation fp32. 8-edge main loop = 4 gathers in flight per 32-lane
// half (latency hiding). Length comes from degf (written by bucket_csr).
// ---------------------------------------------------------------------------
__device__ __forceinline__ void reduce_one(
    const u16* __restrict__ Xb, const int* __restrict__ offsets,
    const float* __restrict__ degf, const int2* __restrict__ edata, int slot,
    int lane, float* __restrict__ S, float* __restrict__ wsumf)
{
    int start = offsets[slot];
    int end = start + (int)degf[slot];
    int half = lane >> 5;
    int q = (lane & 31) * 4;   // element offset within row (4 per lane)
    float4 acc = make_float4(0.f, 0.f, 0.f, 0.f);
    float wacc = 0.f;
    int j = start;
    for (; j + 8 <= end; j += 8) {
        int2 e0 = edata[j + half];
        int2 e1 = edata[j + 2 + half];
        int2 e2 = edata[j + 4 + half];
        int2 e3 = edata[j + 6 + half];
        ushort4 v0 = *(const ushort4*)(Xb + (size_t)(e0.x & 0x7FFF) * D + q);
        ushort4 v1 = *(const ushort4*)(Xb + (size_t)(e1.x & 0x7FFF) * D + q);
        ushort4 v2 = *(const ushort4*)(Xb + (size_t)(e2.x & 0x7FFF) * D + q);
        ushort4 v3 = *(const ushort4*)(Xb + (size_t)(e3.x & 0x7FFF) * D + q);
        float w0 = __int_as_float(e0.y), w1 = __int_as_float(e1.y);
        float w2 = __int_as_float(e2.y), w3 = __int_as_float(e3.y);
        acc.x = fmaf(w0, b2f(v0.x), acc.x); acc.y = fmaf(w0, b2f(v0.y), acc.y);
        acc.z = fmaf(w0, b2f(v0.z), acc.z); acc.w = fmaf(w0, b2f(v0.w), acc.w);
        acc.x = fmaf(w1, b2f(v1.x), acc.x); acc.y = fmaf(w1, b2f(v1.y), acc.y);
        acc.z = fmaf(w1, b2f(v1.z), acc.z); acc.w = fmaf(w1, b2f(v1.w), acc.w);
        acc.x = fmaf(w2, b2f(v2.x), acc.x); acc.y = fmaf(w2, b2f(v2.y), acc.y);
        acc.z = fmaf(w2, b2f(v2.z), acc.z); acc.w = fmaf(w2, b2f(v2.w), acc.w);
        acc.x = fmaf(w3, b2f(v3.x), acc.x); acc.y = fmaf(w3, b2f(v3.y), acc.y);
        acc.z = fmaf(w3, b2f(v3.z), acc.z); acc.w = fmaf(w3, b2f(v3.w), acc.w);
        wacc += w0 + w1 + w2 + w3;
    }
    if (j + 4 <= end) {
        int2 ea = edata[j + half];
        int2 eb = edata[j + 2 + half];
        ushort4 va = *(const ushort4*)(Xb + (size_t)(ea.x & 0x7FFF) * D + q);
        ushort4 vb = *(const ushort4*)(Xb + (size_t)(eb.x & 0x7FFF) * D + q);
        float wa = __int_as_float(ea.y);
        float wb = __int_as_float(eb.y);
        acc.x = fmaf(wa, b2f(va.x), acc.x); acc.y = fmaf(wa, b2f(va.y), acc.y);
        acc.z = fmaf(wa, b2f(va.z), acc.z); acc.w = fmaf(wa, b2f(va.w), acc.w);
        acc.x = fmaf(wb, b2f(vb.x), acc.x); acc.y = fmaf(wb, b2f(vb.y), acc.y);
        acc.z = fmaf(wb, b2f(vb.z), acc.z); acc.w = fmaf(wb, b2f(vb.w), acc.w);
        wacc += wa + wb;
        j += 4;
    }
    for (; j < end; j += 2) {
        int jj = j + half;
        int2 e = edata[jj < end ? jj : (end - 1)];
        float w = (jj < end) ? __int_as_float(e.y) : 0.f;
        ushort4 v = *(const ushort4*)(Xb + (size_t)(e.x & 0x7FFF) * D + q);
        acc.x = fmaf(w, b2f(v.x), acc.x); acc.y = fmaf(w, b2f(v.y), acc.y);
        acc.z = fmaf(w, b2f(v.z), acc.z); acc.w = fmaf(w, b2f(v.w), acc.w);
        wacc += w;
    }
    acc.x += __shfl_xor(acc.x, 32);
    acc.y += __shfl_xor(acc.y, 32);
    acc.z += __shfl_xor(acc.z, 32);
    acc.w += __shfl_xor(acc.w, 32);
    wacc  += __shfl_xor(wacc, 32);
    if (half == 0)
        *(float4*)(S + (size_t)slot * D + q) = acc;
    if (lane == 0 && wsumf) wsumf[slot] = wacc;
}

__global__ __launch_bounds__(256) void reduce_kernel(
    const u16* __restrict__ Xb, const int* __restrict__ offsets,
    const float* __restrict__ degf, const int2* __restrict__ edata,
    int slot0, int nslots, float* __restrict__ S, float* __restrict__ wsumf)
{
    int rel = blockIdx.x * 4 + (threadIdx.x >> 6);
    if (rel >= nslots) return;
    reduce_one(Xb, offsets, degf, edata, slot0 + rel, threadIdx.x & 63, S, wsumf);
}

__global__ __launch_bounds__(256) void reduce_p2_kernel(
    const u16* __restrict__ hw16, const u16* __restrict__ wtt16,
    const u16* __restrict__ wtd16, const int* __restrict__ offsets,
    const float* __restrict__ degf, const int2* __restrict__ edata,
    float* __restrict__ S, float* __restrict__ wsumf)
{
    int rel = blockIdx.x * 4 + (threadIdx.x >> 6);
    if (rel >= NP2) return;
    const u16* X;
    if (rel < NT)                 X = hw16;   // wt
    else if (rel < 2 * NT)        X = wtt16;  // tt
    else if (rel < 2 * NT + NDOC) X = hw16;   // wd
    else                          X = wtd16;  // td
    reduce_one(X, offsets, degf, edata, SEG_WT + rel, threadIdx.x & 63, S, wsumf);
}

// ---------------------------------------------------------------------------
// Y = X @ W  [n x 128] x [128 x 128], optionally normalized; optional bf16
// mirror Yb. k4-tiled inner loop: all LDS reads are b128. FMA k-order
// unchanged (identical numerics to the scalar version).
// ---------------------------------------------------------------------------
__device__ __forceinline__ void mm_body(
    const float* __restrict__ X, const float* __restrict__ Wg,
    float* Wl, float (*xs)[D], int row0, int n, int tid, float acc[4][4])
{
    for (int i = tid; i < D * D / 4; i += 256)
        ((float4*)Wl)[i] = ((const float4*)Wg)[i];
    for (int i = tid; i < 32 * (D / 4); i += 256) {
        int r = i / (D / 4);
        int c4 = i % (D / 4);
        float4 v = make_float4(0.f, 0.f, 0.f, 0.f);
        if (row0 + r < n)
            v = ((const float4*)(X + (long long)(row0 + r) * D))[c4];
        ((float4*)&xs[r][0])[c4] = v;
    }
    __syncthreads();

    int cg = tid & 31;
    int rg = tid >> 5;
    int col0 = cg * 4;
#pragma unroll
    for (int j = 0; j < 4; ++j)
#pragma unroll
        for (int c = 0; c < 4; ++c) acc[j][c] = 0.f;

#pragma unroll 4
    for (int k4 = 0; k4 < D / 4; ++k4) {
        float4 w0 = *(const float4*)&Wl[(k4 * 4 + 0) * D + col0];
        float4 w1 = *(const float4*)&Wl[(k4 * 4 + 1) * D + col0];
        float4 w2 = *(const float4*)&Wl[(k4 * 4 + 2) * D + col0];
        float4 w3 = *(const float4*)&Wl[(k4 * 4 + 3) * D + col0];
#pragma unroll
        for (int j = 0; j < 4; ++j) {
            float4 xv = *(const float4*)&xs[rg + j * 8][k4 * 4];
            acc[j][0] = fmaf(xv.w, w3.x, fmaf(xv.z, w2.x, fmaf(xv.y, w1.x, fmaf(xv.x, w0.x, acc[j][0]))));
            acc[j][1] = fmaf(xv.w, w3.y, fmaf(xv.z, w2.y, fmaf(xv.y, w1.y, fmaf(xv.x, w0.y, acc[j][1]))));
            acc[j][2] = fmaf(xv.w, w3.z, fmaf(xv.z, w2.z, fmaf(xv.y, w1.z, fmaf(xv.x, w0.z, acc[j][2]))));
            acc[j][3] = fmaf(xv.w, w3.w, fmaf(xv.z, w2.w, fmaf(xv.y, w1.w, fmaf(xv.x, w0.w, acc[j][3]))));
        }
    }
}

__global__ __launch_bounds__(256) void mm_kernel(
    const float* __restrict__ X, const float* __restrict__ W,
    const float* __restrict__ deg, const float* __restrict__ wsum,
    const float* __restrict__ bias,
    const float* __restrict__ T, const float* __restrict__ degT,
    float* __restrict__ Y, u16* __restrict__ Yb, int n)
{
    __shared__ float Wl[D * D];
    __shared__ float xs[32][D];
    int tid = threadIdx.x;
    int row0 = blockIdx.x * 32;
    float acc[4][4];
    mm_body(X, W, Wl, xs, row0, n, tid, acc);

    int cg = tid & 31;
    int rg = tid >> 5;
    int col0 = cg * 4;
#pragma unroll
    for (int j = 0; j < 4; ++j) {
        int row = row0 + rg + j * 8;
        if (row >= n) continue;
        float4 y;
        float* yp = &y.x;
        float dg = deg[row];
        float ws = wsum ? wsum[row] : 0.f;
#pragma unroll
        for (int c = 0; c < 4; ++c)
            yp[c] = dg > 0.f ? (acc[j][c] + ws * bias[col0 + c]) / dg : 0.f;
        if (T) {
            float dt = degT[row];
            if (dt > 0.f) {
                float4 tv = *(const float4*)&T[(long long)row * D + col0];
                y.x += tv.x / dt;
                y.y += tv.y / dt;
                y.z += tv.z / dt;
                y.w += tv.w / dt;
            }
        }
        *(float4*)&Y[(long long)row * D + col0] = y;
        if (Yb) {
            ushort4 o;
            o.x = f2b(y.x); o.y = f2b(y.y); o.z = f2b(y.z); o.w = f2b(y.w);
            *(ushort4*)&Yb[(long long)row * D + col0] = o;
        }
    }
}

// ---------------------------------------------------------------------------
// Fused: 4 topic matmuls (td/tt/causal/noise) + causal combine, emitting
// bf16 Wh_td/Wh_tt directly (P round-trip eliminated).
// ---------------------------------------------------------------------------
__global__ __launch_bounds__(256) void topic_prep_kernel(
    const float* __restrict__ X,
    const float* __restrict__ W_td, const float* __restrict__ W_tt,
    const float* __restrict__ W_c,  const float* __restrict__ W_n,
    const float* __restrict__ b_td, const float* __restrict__ b_tt,
    const float* __restrict__ effect, const float* __restrict__ bern_td,
    const float* __restrict__ bern_tt,
    u16* __restrict__ wtd16, u16* __restrict__ wtt16)
{
    __shared__ float Wl[D * D];
    __shared__ float xs[32][D];
    int tid = threadIdx.x;
    int row0 = blockIdx.x * 32;
    const float* Ws[4] = { W_td, W_tt, W_c, W_n };
    float am[4][4][4];
#pragma unroll 1
    for (int m = 0; m < 4; ++m) {
        if (m) __syncthreads();   // previous matrix's compute done before restage
        mm_body(X, Ws[m], Wl, xs, row0, NT, tid, am[m]);
    }
    int cg = tid & 31;
    int rg = tid >> 5;
    int col0 = cg * 4;
#pragma unroll
    for (int j = 0; j < 4; ++j) {
        int row = row0 + rg + j * 8;
        if (row >= NT) continue;
        float eff = effect[row];
        float causal = (eff != 0.f) ? 1.f : 0.f;
        float zero = (eff == 0.f) ? 1.f : 0.f;
        float rmtd = bern_td[row] * zero;
        float rmtt = bern_tt[row] * zero;
        ushort4 otd, ott;
        u16* ptd = &otd.x; u16* ptt = &ott.x;
#pragma unroll
        for (int c = 0; c < 4; ++c) {
            float pc = am[2][j][c], pn = am[3][j][c];
            ptd[c] = f2b(am[0][j][c] + b_td[col0 + c] + causal * pc - rmtd * pn);
            ptt[c] = f2b(am[1][j][c] + b_tt[col0 + c] + causal * pc - rmtt * pn);
        }
        *(ushort4*)&wtd16[(long long)row * D + col0] = otd;
        *(ushort4*)&wtt16[(long long)row * D + col0] = ott;
    }
}

extern "C" void kernel_launch(void* const* d_in, const int* in_sizes, int n_in,
                              void* d_out, int out_size, void* d_ws, size_t ws_size,
                              hipStream_t stream)
{
    const float* feat_word  = (const float*)d_in[0];
    const float* feat_topic = (const float*)d_in[1];
    const float* effect     = (const float*)d_in[2];
    const float* bern_td    = (const float*)d_in[3];
    const float* bern_tt    = (const float*)d_in[4];
    const int*   src_ww = (const int*)d_in[5];
    const int*   dst_ww = (const int*)d_in[6];
    const float* w_ww   = (const float*)d_in[7];
    const int*   src_wt = (const int*)d_in[8];
    const int*   dst_wt = (const int*)d_in[9];
    const float* w_wt   = (const float*)d_in[10];
    const int*   src_wd = (const int*)d_in[11];
    const int*   dst_wd = (const int*)d_in[12];
    const float* w_wd   = (const float*)d_in[13];
    const int*   src_td = (const int*)d_in[14];
    const int*   dst_td = (const int*)d_in[15];
    const float* w_td   = (const float*)d_in[16];
    const int*   src_tt = (const int*)d_in[17];
    const int*   dst_tt = (const int*)d_in[18];
    const float* w_tt   = (const float*)d_in[19];
    const float* W_ww = (const float*)d_in[20];
    const float* b_ww = (const float*)d_in[21];
    const float* W_wt = (const float*)d_in[22];
    const float* b_wt = (const float*)d_in[23];
    const float* W_wd = (const float*)d_in[24];
    const float* b_wd = (const float*)d_in[25];
    const float* W_td = (const float*)d_in[26];
    const float* b_td = (const float*)d_in[27];
    const float* W_tt = (const float*)d_in[28];
    const float* b_tt = (const float*)d_in[29];
    const float* W_causal = (const float*)d_in[30];
    const float* W_noise  = (const float*)d_in[31];

    const int E_ww = in_sizes[5];
    const int E_wt = in_sizes[8];
    const int E_wd = in_sizes[11];
    const int E_td = in_sizes[14];
    const int E_tt = in_sizes[17];
    const int E_total = E_ww + E_wt + E_wd + E_td + E_tt;

    // ---- workspace layout (4-byte units; int2 buffers 8B-aligned) ----
    float* ws = (float*)d_ws;
    float* S      = ws; ws += (long long)NSLOT * D;
    float* degf   = ws; ws += NSLOT;
    float* wsumf  = ws; ws += NSLOT;
    int*   offsets      = (int*)ws; ws += NSLOT + 1;
    int*   bucket_base  = (int*)ws; ws += NBKT + 1;
    int*   bucket_cursor= (int*)ws; ws += NBKT;
    int*   gcur         = (int*)ws; ws += 1;
    ws += ((size_t)(ws - (float*)d_ws) & 1);          // 8B align
    int2*  edataB   = (int2*)ws; ws += (long long)2 * E_total;   // COMPACT coords
    u16*   fw16     = (u16*)ws;  ws += (long long)NW * D / 2;   // bf16 feat_word
    u16*   hw16     = (u16*)ws;  ws += (long long)NW * D / 2;   // bf16 h_word
    u16*   wtd16    = (u16*)ws;  ws += (long long)NT * D / 2;
    u16*   wtt16    = (u16*)ws;  ws += (long long)NT * D / 2;
    // edataA (PADDED coords, cap total ~2.24M int2) overlays S's doc-segment
    // region ((NSLOT-SEG_WD)*D = 5.12M floats = 2.56M int2). Dead before the
    // phase-2 reduce writes those S slots.
    int2*  edataA = (int2*)(S + (long long)SEG_WD * D);

    float* h_word  = (float*)d_out;
    float* h_topic = h_word + (long long)NW * D;
    float* h_doc   = h_topic + (long long)NT * D;

    auto nb = [](long long n) { return (unsigned)((n + 255) / 256); };

    Rels R;
    R.r[0] = { src_ww, dst_ww, w_ww, 0, SEG_WW };
    R.r[1] = { src_wt, dst_wt, w_wt, E_ww, SEG_WT };
    R.r[2] = { src_tt, dst_tt, w_tt, E_ww + E_wt, SEG_TT };
    R.r[3] = { src_wd, dst_wd, w_wd, E_ww + E_wt + E_tt, SEG_WD };
    R.r[4] = { src_td, dst_td, w_td, E_ww + E_wt + E_tt + E_wd, SEG_TD };

    // ---- bf16 gather table for feat_word ----
    f2b_kernel<<<nb((long long)NW * D / 4), 256, 0, stream>>>(
        feat_word, fw16, NW * D / 4);

    // ---- Fused topic-side precompute (4 matmuls + causal combine) ----
    topic_prep_kernel<<<(NT + 31) / 32, 256, 0, stream>>>(
        feat_topic, W_td, W_tt, W_causal, W_noise, b_td, b_tt,
        effect, bern_td, bern_tt, wtd16, wtt16);

    // ---- CSR build: analytic caps/scan -> partition -> per-bucket CSR ----
    cap_scan_kernel<<<1, 256, 0, stream>>>(
        (float)E_ww / NW, (float)E_wt / NT, (float)E_tt / NT,
        (float)E_wd / NDOC, (float)E_td / NDOC, bucket_base, bucket_cursor, gcur);
    unsigned npb = (unsigned)((E_total + EPB - 1) / EPB);
    partition_kernel<<<npb, 256, 0, stream>>>(R, E_total, bucket_cursor, edataA);
    bucket_csr_kernel<<<NBKT, 1024, 0, stream>>>(
        bucket_base, bucket_cursor, edataA, edataB, offsets, degf, gcur);

    // ---- Phase 1: ww reduce + word projection (fp32 out + bf16 mirror) ----
    reduce_kernel<<<(NW + 3) / 4, 256, 0, stream>>>(
        fw16, offsets, degf, edataB, SEG_WW, NW, S, wsumf);
    mm_kernel<<<(NW + 31) / 32, 256, 0, stream>>>(
        S + (long long)SEG_WW * D, W_ww, degf + SEG_WW, wsumf + SEG_WW, b_ww,
        nullptr, nullptr, h_word, hw16, NW);

    // ---- Phase 2: merged reduce over wt/tt/wd/td ----
    reduce_p2_kernel<<<(NP2 + 3) / 4, 256, 0, stream>>>(
        hw16, wtt16, wtd16, offsets, degf, edataB, S, wsumf);

    // ---- Final projections + cross-relation sums ----
    mm_kernel<<<(NT + 31) / 32, 256, 0, stream>>>(
        S + (long long)SEG_WT * D, W_wt, degf + SEG_WT, wsumf + SEG_WT, b_wt,
        S + (long long)SEG_TT * D, degf + SEG_TT, h_topic, nullptr, NT);
    mm_kernel<<<(NDOC + 31) / 32, 256, 0, stream>>>(
        S + (long long)SEG_WD * D, W_wd, degf + SEG_WD, wsumf + SEG_WD, b_wd,
        S + (long long)SEG_TD * D, degf + SEG_TD, h_doc, nullptr, NDOC);

    (void)n_in; (void)in_sizes; (void)out_size; (void)ws_size;
}

// Round 10
// 351.647 us; speedup vs baseline: 1.0933x; 1.0933x over previous
//
#include <hip/hip_runtime.h>

#define D 128
typedef unsigned short u16;
constexpr int NW = 30000;
constexpr int NT = 2000;
constexpr int NDOC = 20000;
constexpr int NSLOT = NW + NT + NT + NDOC + NDOC;   // 74000 destination slots
constexpr int SEG_WW = 0;
constexpr int SEG_WT = NW;                 // 30000
constexpr int SEG_TT = NW + NT;            // 32000
constexpr int SEG_WD = NW + 2 * NT;        // 34000
constexpr int SEG_TD = NW + 2 * NT + NDOC; // 54000
constexpr int NP2 = NT + NT + NDOC + NDOC; // 44000 phase-2 slots

constexpr int BWS = 128;                    // slots per bucket (pow2: slot>>7)
constexpr int NBKT = (NSLOT + BWS - 1) / BWS;  // 579
constexpr int EPB = 2048;                   // edges per partition block (grid ~704)

struct RelDesc { const int* src; const int* dst; const float* w; int e0; int seg; };
struct Rels { RelDesc r[5]; };

__device__ __forceinline__ void resolve_rel(const Rels& R, int e,
    const int*& srcp, const int*& dstp, const float*& wp, int& le, int& seg)
{
    int k;
    if (e < R.r[1].e0) k = 0;
    else if (e < R.r[2].e0) k = 1;
    else if (e < R.r[3].e0) k = 2;
    else if (e < R.r[4].e0) k = 3;
    else k = 4;
    srcp = R.r[k].src; dstp = R.r[k].dst; wp = R.r[k].w;
    le = e - R.r[k].e0; seg = R.r[k].seg;
}

__device__ __forceinline__ float b2f(u16 h)
{
    return __uint_as_float(((unsigned)h) << 16);
}
__device__ __forceinline__ u16 f2b(float f)   // round-to-nearest-even
{
    unsigned u = __float_as_uint(f);
    return (u16)((u + 0x7FFF + ((u >> 16) & 1)) >> 16);
}

// ---------------------------------------------------------------------------
// fp32 -> bf16 table conversion (feat_word): 4 elements per thread.
// ---------------------------------------------------------------------------
__global__ __launch_bounds__(256) void f2b_kernel(
    const float* __restrict__ X, u16* __restrict__ Y, int n4)
{
    int i = blockIdx.x * 256 + threadIdx.x;
    if (i >= n4) return;
    float4 v = ((const float4*)X)[i];
    ushort4 o;
    o.x = f2b(v.x); o.y = f2b(v.y); o.z = f2b(v.z); o.w = f2b(v.w);
    ((ushort4*)Y)[i] = o;
}

// ---------------------------------------------------------------------------
// Analytic bucket capacities + prefix scan -> bucket_base/cursor (PADDED
// coordinates for edataA, which is sized for them). Zeroes the compaction
// cursor. cap_k = 1.5 * expected + 128 (many-sigma margin, uniform dst).
// ---------------------------------------------------------------------------
__global__ __launch_bounds__(256) void cap_scan_kernel(
    float m_ww, float m_wt, float m_tt, float m_wd, float m_td,
    int* __restrict__ bucket_base, int* __restrict__ bucket_cursor,
    int* __restrict__ gcur)
{
    __shared__ int chs[256];
    __shared__ int vals[256 * 3];
    int tid = threadIdx.x;
    if (tid == 0) *gcur = 0;
    int s = 0;
    for (int j = 0; j < 3; ++j) {
        int k = tid * 3 + j;
        int c = 0;
        if (k < NBKT) {
            int a = k * BWS, b = min(a + BWS, NSLOT);
            auto ov = [&](int lo, int hi) {
                return (float)max(0, min(b, hi) - max(a, lo));
            };
            float ex = ov(SEG_WW, SEG_WT) * m_ww + ov(SEG_WT, SEG_TT) * m_wt
                     + ov(SEG_TT, SEG_WD) * m_tt + ov(SEG_WD, SEG_TD) * m_wd
                     + ov(SEG_TD, NSLOT) * m_td;
            c = (int)(ex * 1.5f) + 128;
        }
        vals[tid * 3 + j] = c;
        s += c;
    }
    chs[tid] = s;
    __syncthreads();
    for (int off = 1; off < 256; off <<= 1) {
        int t = (tid >= off) ? chs[tid - off] : 0;
        __syncthreads();
        chs[tid] += t;
        __syncthreads();
    }
    int run = (tid == 0) ? 0 : chs[tid - 1];
    for (int j = 0; j < 3; ++j) {
        int k = tid * 3 + j;
        if (k < NBKT) {
            bucket_base[k] = run;
            bucket_cursor[k] = run;
            run += vals[tid * 3 + j];
        }
    }
}

// ---------------------------------------------------------------------------
// A3: partition edges into capacity-padded bucket regions of edataA. One
// global atomic per (block,bucket); writes are contiguous chunks.
// Entry: x = src | (dloc<<15), y = w bits.
// ---------------------------------------------------------------------------
__global__ __launch_bounds__(256) void partition_kernel(
    Rels R, int Etot, int* __restrict__ bucket_cursor, int2* __restrict__ edataA)
{
    __shared__ int hist[NBKT];
    __shared__ int baseL[NBKT];
    __shared__ u16 bkt[EPB];
    __shared__ unsigned char dl[EPB];
    int tid = threadIdx.x;
    for (int i = tid; i < NBKT; i += 256) hist[i] = 0;
    __syncthreads();
    int base_e = blockIdx.x * EPB;
    for (int r = 0; r < EPB / 256; ++r) {
        int idx = r * 256 + tid;
        int e = base_e + idx;
        if (e < Etot) {
            const int *srcp, *dstp; const float* wp; int le, seg;
            resolve_rel(R, e, srcp, dstp, wp, le, seg);
            int g = seg + dstp[le];
            bkt[idx] = (u16)(g >> 7);
            dl[idx] = (unsigned char)(g & 127);
            atomicAdd(&hist[g >> 7], 1);
        } else {
            bkt[idx] = 0xFFFF;
        }
    }
    __syncthreads();
    for (int i = tid; i < NBKT; i += 256)
        baseL[i] = hist[i] ? atomicAdd(&bucket_cursor[i], hist[i]) : 0;
    __syncthreads();
    for (int i = tid; i < NBKT; i += 256) hist[i] = 0;
    __syncthreads();
    for (int r = 0; r < EPB / 256; ++r) {
        int idx = r * 256 + tid;
        int e = base_e + idx;
        if (e < Etot) {
            const int *srcp, *dstp; const float* wp; int le, seg;
            resolve_rel(R, e, srcp, dstp, wp, le, seg);
            int b = bkt[idx];
            int rk = atomicAdd(&hist[b], 1);
            edataA[baseL[b] + rk] =
                make_int2(srcp[le] | ((int)dl[idx] << 15), __float_as_int(wp[le]));
        }
    }
}

// ---------------------------------------------------------------------------
// B: one block (1024 threads) per bucket. LDS histogram over 128 slots ->
// scan -> COMPACT: claim nk contiguous entries of edataB via one global
// atomic (gcur), so edataB indices stay < E_total even though edataA uses
// padded coordinates. Emits offsets + degf + edges in CSR order.
// ---------------------------------------------------------------------------
__global__ __launch_bounds__(1024) void bucket_csr_kernel(
    const int* __restrict__ bucket_base, const int* __restrict__ bucket_cursor,
    const int2* __restrict__ edataA, int2* __restrict__ edataB,
    int* __restrict__ offsets, float* __restrict__ degf, int* __restrict__ gcur)
{
    int k = blockIdx.x;
    int bstart = bucket_base[k], bend = bucket_cursor[k];
    int nk = bend - bstart;
    __shared__ int h2[BWS];
    __shared__ int exc[BWS];
    __shared__ int cbase;
    int tid = threadIdx.x;
    if (tid == 0) cbase = atomicAdd(gcur, nk);   // compacted output base
    if (tid < BWS) h2[tid] = 0;
    __syncthreads();
    for (int i = bstart + tid; i < bend; i += 1024) {
        int dloc = (edataA[i].x >> 15) & 127;
        atomicAdd(&h2[dloc], 1);
    }
    __syncthreads();
    if (tid < BWS) exc[tid] = h2[tid];
    __syncthreads();
    for (int off = 1; off < BWS; off <<= 1) {
        int t = 0;
        if (tid < BWS && tid >= off) t = exc[tid - off];
        __syncthreads();
        if (tid < BWS) exc[tid] += t;
        __syncthreads();
    }
    if (tid < BWS) exc[tid] -= h2[tid];   // exclusive
    __syncthreads();
    int slot0 = k * BWS;
    if (tid < BWS && slot0 + tid < NSLOT) {
        offsets[slot0 + tid] = cbase + exc[tid];
        degf[slot0 + tid] = (float)h2[tid];
    }
    __syncthreads();
    if (tid < BWS) h2[tid] = 0;
    __syncthreads();
    for (int i = bstart + tid; i < bend; i += 1024) {
        int2 e = edataA[i];
        int dloc = (e.x >> 15) & 127;
        int rk = atomicAdd(&h2[dloc], 1);
        edataB[cbase + exc[dloc] + rk] = e;
    }
}

// ---------------------------------------------------------------------------
// Segmented reduction core (one wave per dst slot). Gather table bf16,
// accumulation fp32. 8-edge main loop = 4 gathers in flight per 32-lane
// half (latency hiding). Length comes from degf (written by bucket_csr).
// ---------------------------------------------------------------------------
__device__ __forceinline__ void reduce_one(
    const u16* __restrict__ Xb, const int* __restrict__ offsets,
    const float* __restrict__ degf, const int2* __restrict__ edata, int slot,
    int lane, float* __restrict__ S, float* __restrict__ wsumf)
{
    int start = offsets[slot];
    int end = start + (int)degf[slot];
    int half = lane >> 5;
    int q = (lane & 31) * 4;   // element offset within row (4 per lane)
    float4 acc = make_float4(0.f, 0.f, 0.f, 0.f);
    float wacc = 0.f;
    int j = start;
    for (; j + 8 <= end; j += 8) {
        int2 e0 = edata[j + half];
        int2 e1 = edata[j + 2 + half];
        int2 e2 = edata[j + 4 + half];
        int2 e3 = edata[j + 6 + half];
        ushort4 v0 = *(const ushort4*)(Xb + (size_t)(e0.x & 0x7FFF) * D + q);
        ushort4 v1 = *(const ushort4*)(Xb + (size_t)(e1.x & 0x7FFF) * D + q);
        ushort4 v2 = *(const ushort4*)(Xb + (size_t)(e2.x & 0x7FFF) * D + q);
        ushort4 v3 = *(const ushort4*)(Xb + (size_t)(e3.x & 0x7FFF) * D + q);
        float w0 = __int_as_float(e0.y), w1 = __int_as_float(e1.y);
        float w2 = __int_as_float(e2.y), w3 = __int_as_float(e3.y);
        acc.x = fmaf(w0, b2f(v0.x), acc.x); acc.y = fmaf(w0, b2f(v0.y), acc.y);
        acc.z = fmaf(w0, b2f(v0.z), acc.z); acc.w = fmaf(w0, b2f(v0.w), acc.w);
        acc.x = fmaf(w1, b2f(v1.x), acc.x); acc.y = fmaf(w1, b2f(v1.y), acc.y);
        acc.z = fmaf(w1, b2f(v1.z), acc.z); acc.w = fmaf(w1, b2f(v1.w), acc.w);
        acc.x = fmaf(w2, b2f(v2.x), acc.x); acc.y = fmaf(w2, b2f(v2.y), acc.y);
        acc.z = fmaf(w2, b2f(v2.z), acc.z); acc.w = fmaf(w2, b2f(v2.w), acc.w);
        acc.x = fmaf(w3, b2f(v3.x), acc.x); acc.y = fmaf(w3, b2f(v3.y), acc.y);
        acc.z = fmaf(w3, b2f(v3.z), acc.z); acc.w = fmaf(w3, b2f(v3.w), acc.w);
        wacc += w0 + w1 + w2 + w3;
    }
    if (j + 4 <= end) {
        int2 ea = edata[j + half];
        int2 eb = edata[j + 2 + half];
        ushort4 va = *(const ushort4*)(Xb + (size_t)(ea.x & 0x7FFF) * D + q);
        ushort4 vb = *(const ushort4*)(Xb + (size_t)(eb.x & 0x7FFF) * D + q);
        float wa = __int_as_float(ea.y);
        float wb = __int_as_float(eb.y);
        acc.x = fmaf(wa, b2f(va.x), acc.x); acc.y = fmaf(wa, b2f(va.y), acc.y);
        acc.z = fmaf(wa, b2f(va.z), acc.z); acc.w = fmaf(wa, b2f(va.w), acc.w);
        acc.x = fmaf(wb, b2f(vb.x), acc.x); acc.y = fmaf(wb, b2f(vb.y), acc.y);
        acc.z = fmaf(wb, b2f(vb.z), acc.z); acc.w = fmaf(wb, b2f(vb.w), acc.w);
        wacc += wa + wb;
        j += 4;
    }
    for (; j < end; j += 2) {
        int jj = j + half;
        int2 e = edata[jj < end ? jj : (end - 1)];
        float w = (jj < end) ? __int_as_float(e.y) : 0.f;
        ushort4 v = *(const ushort4*)(Xb + (size_t)(e.x & 0x7FFF) * D + q);
        acc.x = fmaf(w, b2f(v.x), acc.x); acc.y = fmaf(w, b2f(v.y), acc.y);
        acc.z = fmaf(w, b2f(v.z), acc.z); acc.w = fmaf(w, b2f(v.w), acc.w);
        wacc += w;
    }
    acc.x += __shfl_xor(acc.x, 32);
    acc.y += __shfl_xor(acc.y, 32);
    acc.z += __shfl_xor(acc.z, 32);
    acc.w += __shfl_xor(acc.w, 32);
    wacc  += __shfl_xor(wacc, 32);
    if (half == 0)
        *(float4*)(S + (size_t)slot * D + q) = acc;
    if (lane == 0 && wsumf) wsumf[slot] = wacc;
}

__global__ __launch_bounds__(256) void reduce_kernel(
    const u16* __restrict__ Xb, const int* __restrict__ offsets,
    const float* __restrict__ degf, const int2* __restrict__ edata,
    int slot0, int nslots, float* __restrict__ S, float* __restrict__ wsumf)
{
    int rel = blockIdx.x * 4 + (threadIdx.x >> 6);
    if (rel >= nslots) return;
    reduce_one(Xb, offsets, degf, edata, slot0 + rel, threadIdx.x & 63, S, wsumf);
}

__global__ __launch_bounds__(256) void reduce_p2_kernel(
    const u16* __restrict__ hw16, const u16* __restrict__ wtt16,
    const u16* __restrict__ wtd16, const int* __restrict__ offsets,
    const float* __restrict__ degf, const int2* __restrict__ edata,
    float* __restrict__ S, float* __restrict__ wsumf)
{
    int rel = blockIdx.x * 4 + (threadIdx.x >> 6);
    if (rel >= NP2) return;
    const u16* X;
    if (rel < NT)                 X = hw16;   // wt
    else if (rel < 2 * NT)        X = wtt16;  // tt
    else if (rel < 2 * NT + NDOC) X = hw16;   // wd
    else                          X = wtd16;  // td
    reduce_one(X, offsets, degf, edata, SEG_WT + rel, threadIdx.x & 63, S, wsumf);
}

// ---------------------------------------------------------------------------
// Y = X @ W  [n x 128] x [128 x 128]. k4-tiled inner loop: all LDS reads are
// b128. FMA k-order matches the scalar version (identical numerics).
// ---------------------------------------------------------------------------
__device__ __forceinline__ void mm_body(
    const float* __restrict__ X, const float* __restrict__ Wg,
    float* Wl, float (*xs)[D], int row0, int n, int tid, float acc[4][4])
{
    for (int i = tid; i < D * D / 4; i += 256)
        ((float4*)Wl)[i] = ((const float4*)Wg)[i];
    for (int i = tid; i < 32 * (D / 4); i += 256) {
        int r = i / (D / 4);
        int c4 = i % (D / 4);
        float4 v = make_float4(0.f, 0.f, 0.f, 0.f);
        if (row0 + r < n)
            v = ((const float4*)(X + (long long)(row0 + r) * D))[c4];
        ((float4*)&xs[r][0])[c4] = v;
    }
    __syncthreads();

    int cg = tid & 31;
    int rg = tid >> 5;
    int col0 = cg * 4;
#pragma unroll
    for (int j = 0; j < 4; ++j)
#pragma unroll
        for (int c = 0; c < 4; ++c) acc[j][c] = 0.f;

#pragma unroll 4
    for (int k4 = 0; k4 < D / 4; ++k4) {
        float4 w0 = *(const float4*)&Wl[(k4 * 4 + 0) * D + col0];
        float4 w1 = *(const float4*)&Wl[(k4 * 4 + 1) * D + col0];
        float4 w2 = *(const float4*)&Wl[(k4 * 4 + 2) * D + col0];
        float4 w3 = *(const float4*)&Wl[(k4 * 4 + 3) * D + col0];
#pragma unroll
        for (int j = 0; j < 4; ++j) {
            float4 xv = *(const float4*)&xs[rg + j * 8][k4 * 4];
            acc[j][0] = fmaf(xv.w, w3.x, fmaf(xv.z, w2.x, fmaf(xv.y, w1.x, fmaf(xv.x, w0.x, acc[j][0]))));
            acc[j][1] = fmaf(xv.w, w3.y, fmaf(xv.z, w2.y, fmaf(xv.y, w1.y, fmaf(xv.x, w0.y, acc[j][1]))));
            acc[j][2] = fmaf(xv.w, w3.z, fmaf(xv.z, w2.z, fmaf(xv.y, w1.z, fmaf(xv.x, w0.z, acc[j][2]))));
            acc[j][3] = fmaf(xv.w, w3.w, fmaf(xv.z, w2.w, fmaf(xv.y, w1.w, fmaf(xv.x, w0.w, acc[j][3]))));
        }
    }
}

__global__ __launch_bounds__(256) void mm_kernel(
    const float* __restrict__ X, const float* __restrict__ W,
    const float* __restrict__ deg, const float* __restrict__ wsum,
    const float* __restrict__ bias,
    const float* __restrict__ T, const float* __restrict__ degT,
    float* __restrict__ Y, u16* __restrict__ Yb, int n)
{
    __shared__ float Wl[D * D];
    __shared__ float xs[32][D];
    int tid = threadIdx.x;
    int row0 = blockIdx.x * 32;
    float acc[4][4];
    mm_body(X, W, Wl, xs, row0, n, tid, acc);

    int cg = tid & 31;
    int rg = tid >> 5;
    int col0 = cg * 4;
#pragma unroll
    for (int j = 0; j < 4; ++j) {
        int row = row0 + rg + j * 8;
        if (row >= n) continue;
        float4 y;
        float* yp = &y.x;
        float dg = deg[row];
        float ws = wsum ? wsum[row] : 0.f;
#pragma unroll
        for (int c = 0; c < 4; ++c)
            yp[c] = dg > 0.f ? (acc[j][c] + ws * bias[col0 + c]) / dg : 0.f;
        if (T) {
            float dt = degT[row];
            if (dt > 0.f) {
                float4 tv = *(const float4*)&T[(long long)row * D + col0];
                y.x += tv.x / dt;
                y.y += tv.y / dt;
                y.z += tv.z / dt;
                y.w += tv.w / dt;
            }
        }
        *(float4*)&Y[(long long)row * D + col0] = y;
        if (Yb) {
            ushort4 o;
            o.x = f2b(y.x); o.y = f2b(y.y); o.z = f2b(y.z); o.w = f2b(y.w);
            *(ushort4*)&Yb[(long long)row * D + col0] = o;
        }
    }
}

// 4 simultaneous [NT x 128] @ [128 x 128] products (blockIdx.y selects W/P).
// Separate kernel (NOT fused with combine): fusing to 63 blocks starved the
// machine (OccupancyPercent 2.3, 48us — round 9). 63x4 blocks is 4x parallel.
struct MM4 { const float* W[4]; float* P[4]; };
__global__ __launch_bounds__(256) void mm4_kernel(const float* __restrict__ X, MM4 p, int n)
{
    __shared__ float Wl[D * D];
    __shared__ float xs[32][D];
    int tid = threadIdx.x;
    int row0 = blockIdx.x * 32;
    float acc[4][4];
    mm_body(X, p.W[blockIdx.y], Wl, xs, row0, n, tid, acc);
    float* Y = p.P[blockIdx.y];

    int cg = tid & 31;
    int rg = tid >> 5;
    int col0 = cg * 4;
#pragma unroll
    for (int j = 0; j < 4; ++j) {
        int row = row0 + rg + j * 8;
        if (row >= n) continue;
        *(float4*)&Y[(long long)row * D + col0] =
            make_float4(acc[j][0], acc[j][1], acc[j][2], acc[j][3]);
    }
}

// ---------------------------------------------------------------------------
// Wh_td = P_td + b_td + causal*Pc - rm_td*Pn ; same for tt. Emits bf16.
// ---------------------------------------------------------------------------
__global__ __launch_bounds__(256) void combine_topic_kernel(
    const float* __restrict__ P_td, const float* __restrict__ P_tt,
    const float* __restrict__ Pc, const float* __restrict__ Pn,
    const float* __restrict__ effect, const float* __restrict__ bern_td,
    const float* __restrict__ bern_tt,
    const float* __restrict__ b_td, const float* __restrict__ b_tt,
    u16* __restrict__ wtd16, u16* __restrict__ wtt16)
{
    int i = blockIdx.x * 256 + threadIdx.x;
    if (i >= NT * D) return;
    int row = i >> 7;
    int col = i & (D - 1);
    float eff = effect[row];
    float causal = (eff != 0.f) ? 1.f : 0.f;
    float zero = (eff == 0.f) ? 1.f : 0.f;
    float rmtd = bern_td[row] * zero;
    float rmtt = bern_tt[row] * zero;
    float pc = Pc[i];
    float pn = Pn[i];
    wtd16[i] = f2b(P_td[i] + b_td[col] + causal * pc - rmtd * pn);
    wtt16[i] = f2b(P_tt[i] + b_tt[col] + causal * pc - rmtt * pn);
}

extern "C" void kernel_launch(void* const* d_in, const int* in_sizes, int n_in,
                              void* d_out, int out_size, void* d_ws, size_t ws_size,
                              hipStream_t stream)
{
    const float* feat_word  = (const float*)d_in[0];
    const float* feat_topic = (const float*)d_in[1];
    const float* effect     = (const float*)d_in[2];
    const float* bern_td    = (const float*)d_in[3];
    const float* bern_tt    = (const float*)d_in[4];
    const int*   src_ww = (const int*)d_in[5];
    const int*   dst_ww = (const int*)d_in[6];
    const float* w_ww   = (const float*)d_in[7];
    const int*   src_wt = (const int*)d_in[8];
    const int*   dst_wt = (const int*)d_in[9];
    const float* w_wt   = (const float*)d_in[10];
    const int*   src_wd = (const int*)d_in[11];
    const int*   dst_wd = (const int*)d_in[12];
    const float* w_wd   = (const float*)d_in[13];
    const int*   src_td = (const int*)d_in[14];
    const int*   dst_td = (const int*)d_in[15];
    const float* w_td   = (const float*)d_in[16];
    const int*   src_tt = (const int*)d_in[17];
    const int*   dst_tt = (const int*)d_in[18];
    const float* w_tt   = (const float*)d_in[19];
    const float* W_ww = (const float*)d_in[20];
    const float* b_ww = (const float*)d_in[21];
    const float* W_wt = (const float*)d_in[22];
    const float* b_wt = (const float*)d_in[23];
    const float* W_wd = (const float*)d_in[24];
    const float* b_wd = (const float*)d_in[25];
    const float* W_td = (const float*)d_in[26];
    const float* b_td = (const float*)d_in[27];
    const float* W_tt = (const float*)d_in[28];
    const float* b_tt = (const float*)d_in[29];
    const float* W_causal = (const float*)d_in[30];
    const float* W_noise  = (const float*)d_in[31];

    const int E_ww = in_sizes[5];
    const int E_wt = in_sizes[8];
    const int E_wd = in_sizes[11];
    const int E_td = in_sizes[14];
    const int E_tt = in_sizes[17];
    const int E_total = E_ww + E_wt + E_wd + E_td + E_tt;
    // padded edataA capacity: sum of per-bucket caps <= 1.5*E_total + 128*NBKT
    const long long capA = (long long)(1.5 * E_total) + 128LL * NBKT + 256;

    // ---- workspace layout (4-byte units; dedicated regions, NO overlays) ----
    float* ws = (float*)d_ws;
    float* S      = ws; ws += (long long)NSLOT * D;
    float* degf   = ws; ws += NSLOT;
    float* wsumf  = ws; ws += NSLOT;
    int*   offsets      = (int*)ws; ws += NSLOT + 1;
    int*   bucket_base  = (int*)ws; ws += NBKT + 1;
    int*   bucket_cursor= (int*)ws; ws += NBKT;
    int*   gcur         = (int*)ws; ws += 1;
    ws += ((size_t)(ws - (float*)d_ws) & 1);          // 8B align
    int2*  edataB   = (int2*)ws; ws += (long long)2 * E_total;   // compact coords
    int2*  edataA   = (int2*)ws; ws += 2 * capA;                 // padded coords
    float* P_td  = ws; ws += (long long)NT * D;
    float* P_tt  = ws; ws += (long long)NT * D;
    float* Pc    = ws; ws += (long long)NT * D;
    float* Pn    = ws; ws += (long long)NT * D;
    u16*   fw16     = (u16*)ws;  ws += (long long)NW * D / 2;   // bf16 feat_word
    u16*   hw16     = (u16*)ws;  ws += (long long)NW * D / 2;   // bf16 h_word
    u16*   wtd16    = (u16*)ws;  ws += (long long)NT * D / 2;
    u16*   wtt16    = (u16*)ws;  ws += (long long)NT * D / 2;

    float* h_word  = (float*)d_out;
    float* h_topic = h_word + (long long)NW * D;
    float* h_doc   = h_topic + (long long)NT * D;

    auto nb = [](long long n) { return (unsigned)((n + 255) / 256); };

    Rels R;
    R.r[0] = { src_ww, dst_ww, w_ww, 0, SEG_WW };
    R.r[1] = { src_wt, dst_wt, w_wt, E_ww, SEG_WT };
    R.r[2] = { src_tt, dst_tt, w_tt, E_ww + E_wt, SEG_TT };
    R.r[3] = { src_wd, dst_wd, w_wd, E_ww + E_wt + E_tt, SEG_WD };
    R.r[4] = { src_td, dst_td, w_td, E_ww + E_wt + E_tt + E_wd, SEG_TD };

    // ---- bf16 gather table for feat_word ----
    f2b_kernel<<<nb((long long)NW * D / 4), 256, 0, stream>>>(
        feat_word, fw16, NW * D / 4);

    // ---- Topic-side precompute: 4-way parallel matmuls + combine ----
    MM4 m4;
    m4.W[0] = W_td; m4.W[1] = W_tt; m4.W[2] = W_causal; m4.W[3] = W_noise;
    m4.P[0] = P_td; m4.P[1] = P_tt; m4.P[2] = Pc;       m4.P[3] = Pn;
    mm4_kernel<<<dim3((NT + 31) / 32, 4), 256, 0, stream>>>(feat_topic, m4, NT);
    combine_topic_kernel<<<nb(NT * D), 256, 0, stream>>>(
        P_td, P_tt, Pc, Pn, effect, bern_td, bern_tt, b_td, b_tt, wtd16, wtt16);

    // ---- CSR build: analytic caps/scan -> partition -> per-bucket CSR ----
    cap_scan_kernel<<<1, 256, 0, stream>>>(
        (float)E_ww / NW, (float)E_wt / NT, (float)E_tt / NT,
        (float)E_wd / NDOC, (float)E_td / NDOC, bucket_base, bucket_cursor, gcur);
    unsigned npb = (unsigned)((E_total + EPB - 1) / EPB);
    partition_kernel<<<npb, 256, 0, stream>>>(R, E_total, bucket_cursor, edataA);
    bucket_csr_kernel<<<NBKT, 1024, 0, stream>>>(
        bucket_base, bucket_cursor, edataA, edataB, offsets, degf, gcur);

    // ---- Phase 1: ww reduce + word projection (fp32 out + bf16 mirror) ----
    reduce_kernel<<<(NW + 3) / 4, 256, 0, stream>>>(
        fw16, offsets, degf, edataB, SEG_WW, NW, S, wsumf);
    mm_kernel<<<(NW + 31) / 32, 256, 0, stream>>>(
        S + (long long)SEG_WW * D, W_ww, degf + SEG_WW, wsumf + SEG_WW, b_ww,
        nullptr, nullptr, h_word, hw16, NW);

    // ---- Phase 2: merged reduce over wt/tt/wd/td ----
    reduce_p2_kernel<<<(NP2 + 3) / 4, 256, 0, stream>>>(
        hw16, wtt16, wtd16, offsets, degf, edataB, S, wsumf);

    // ---- Final projections + cross-relation sums ----
    mm_kernel<<<(NT + 31) / 32, 256, 0, stream>>>(
        S + (long long)SEG_WT * D, W_wt, degf + SEG_WT, wsumf + SEG_WT, b_wt,
        S + (long long)SEG_TT * D, degf + SEG_TT, h_topic, nullptr, NT);
    mm_kernel<<<(NDOC + 31) / 32, 256, 0, stream>>>(
        S + (long long)SEG_WD * D, W_wd, degf + SEG_WD, wsumf + SEG_WD, b_wd,
        S + (long long)SEG_TD * D, degf + SEG_TD, h_doc, nullptr, NDOC);

    (void)n_in; (void)in_sizes; (void)out_size; (void)ws_size;
}

// Round 11
// 333.513 us; speedup vs baseline: 1.1528x; 1.0544x over previous
//
#include <hip/hip_runtime.h>

#define D 128
typedef unsigned short u16;
constexpr int NW = 30000;
constexpr int NT = 2000;
constexpr int NDOC = 20000;
constexpr int NSLOT = NW + NT + NT + NDOC + NDOC;   // 74000 destination slots
constexpr int SEG_WW = 0;
constexpr int SEG_WT = NW;                 // 30000
constexpr int SEG_TT = NW + NT;            // 32000
constexpr int SEG_WD = NW + 2 * NT;        // 34000
constexpr int SEG_TD = NW + 2 * NT + NDOC; // 54000
constexpr int NP2 = NT + NT + NDOC + NDOC; // 44000 phase-2 slots

constexpr int BWS = 128;                    // slots per bucket (pow2: slot>>7)
constexpr int NBKT = (NSLOT + BWS - 1) / BWS;  // 579
constexpr int EPB = 2048;                   // edges per partition block (grid ~704)

struct RelDesc { const int* src; const int* dst; const float* w; int e0; int seg; };
struct Rels { RelDesc r[5]; };

__device__ __forceinline__ void resolve_rel(const Rels& R, int e,
    const int*& srcp, const int*& dstp, const float*& wp, int& le, int& seg)
{
    int k;
    if (e < R.r[1].e0) k = 0;
    else if (e < R.r[2].e0) k = 1;
    else if (e < R.r[3].e0) k = 2;
    else if (e < R.r[4].e0) k = 3;
    else k = 4;
    srcp = R.r[k].src; dstp = R.r[k].dst; wp = R.r[k].w;
    le = e - R.r[k].e0; seg = R.r[k].seg;
}

__device__ __forceinline__ float b2f(u16 h)
{
    return __uint_as_float(((unsigned)h) << 16);
}
__device__ __forceinline__ u16 f2b(float f)   // round-to-nearest-even
{
    unsigned u = __float_as_uint(f);
    return (u16)((u + 0x7FFF + ((u >> 16) & 1)) >> 16);
}

// ---------------------------------------------------------------------------
// fp32 -> bf16 table conversion (feat_word): 4 elements per thread.
// ---------------------------------------------------------------------------
__global__ __launch_bounds__(256) void f2b_kernel(
    const float* __restrict__ X, u16* __restrict__ Y, int n4)
{
    int i = blockIdx.x * 256 + threadIdx.x;
    if (i >= n4) return;
    float4 v = ((const float4*)X)[i];
    ushort4 o;
    o.x = f2b(v.x); o.y = f2b(v.y); o.z = f2b(v.z); o.w = f2b(v.w);
    ((ushort4*)Y)[i] = o;
}

// ---------------------------------------------------------------------------
// Analytic bucket capacities + prefix scan -> bucket_base/cursor (PADDED
// coordinates for edataA, which is sized for them). Zeroes the compaction
// cursor. cap_k = 1.5 * expected + 128 (many-sigma margin, uniform dst).
// ---------------------------------------------------------------------------
__global__ __launch_bounds__(256) void cap_scan_kernel(
    float m_ww, float m_wt, float m_tt, float m_wd, float m_td,
    int* __restrict__ bucket_base, int* __restrict__ bucket_cursor,
    int* __restrict__ gcur)
{
    __shared__ int chs[256];
    __shared__ int vals[256 * 3];
    int tid = threadIdx.x;
    if (tid == 0) *gcur = 0;
    int s = 0;
    for (int j = 0; j < 3; ++j) {
        int k = tid * 3 + j;
        int c = 0;
        if (k < NBKT) {
            int a = k * BWS, b = min(a + BWS, NSLOT);
            auto ov = [&](int lo, int hi) {
                return (float)max(0, min(b, hi) - max(a, lo));
            };
            float ex = ov(SEG_WW, SEG_WT) * m_ww + ov(SEG_WT, SEG_TT) * m_wt
                     + ov(SEG_TT, SEG_WD) * m_tt + ov(SEG_WD, SEG_TD) * m_wd
                     + ov(SEG_TD, NSLOT) * m_td;
            c = (int)(ex * 1.5f) + 128;
        }
        vals[tid * 3 + j] = c;
        s += c;
    }
    chs[tid] = s;
    __syncthreads();
    for (int off = 1; off < 256; off <<= 1) {
        int t = (tid >= off) ? chs[tid - off] : 0;
        __syncthreads();
        chs[tid] += t;
        __syncthreads();
    }
    int run = (tid == 0) ? 0 : chs[tid - 1];
    for (int j = 0; j < 3; ++j) {
        int k = tid * 3 + j;
        if (k < NBKT) {
            bucket_base[k] = run;
            bucket_cursor[k] = run;
            run += vals[tid * 3 + j];
        }
    }
}

// ---------------------------------------------------------------------------
// A3: partition edges into capacity-padded bucket regions of edataA. One
// global atomic per (block,bucket); writes are contiguous chunks.
// Entry: x = src | (dloc<<15), y = w bits.
// ---------------------------------------------------------------------------
__global__ __launch_bounds__(256) void partition_kernel(
    Rels R, int Etot, int* __restrict__ bucket_cursor, int2* __restrict__ edataA)
{
    __shared__ int hist[NBKT];
    __shared__ int baseL[NBKT];
    __shared__ u16 bkt[EPB];
    __shared__ unsigned char dl[EPB];
    int tid = threadIdx.x;
    for (int i = tid; i < NBKT; i += 256) hist[i] = 0;
    __syncthreads();
    int base_e = blockIdx.x * EPB;
    for (int r = 0; r < EPB / 256; ++r) {
        int idx = r * 256 + tid;
        int e = base_e + idx;
        if (e < Etot) {
            const int *srcp, *dstp; const float* wp; int le, seg;
            resolve_rel(R, e, srcp, dstp, wp, le, seg);
            int g = seg + dstp[le];
            bkt[idx] = (u16)(g >> 7);
            dl[idx] = (unsigned char)(g & 127);
            atomicAdd(&hist[g >> 7], 1);
        } else {
            bkt[idx] = 0xFFFF;
        }
    }
    __syncthreads();
    for (int i = tid; i < NBKT; i += 256)
        baseL[i] = hist[i] ? atomicAdd(&bucket_cursor[i], hist[i]) : 0;
    __syncthreads();
    for (int i = tid; i < NBKT; i += 256) hist[i] = 0;
    __syncthreads();
    for (int r = 0; r < EPB / 256; ++r) {
        int idx = r * 256 + tid;
        int e = base_e + idx;
        if (e < Etot) {
            const int *srcp, *dstp; const float* wp; int le, seg;
            resolve_rel(R, e, srcp, dstp, wp, le, seg);
            int b = bkt[idx];
            int rk = atomicAdd(&hist[b], 1);
            edataA[baseL[b] + rk] =
                make_int2(srcp[le] | ((int)dl[idx] << 15), __float_as_int(wp[le]));
        }
    }
}

// ---------------------------------------------------------------------------
// B: one block (1024 threads) per bucket. LDS histogram over 128 slots ->
// scan -> COMPACT: claim nk contiguous entries of edataB via one global
// atomic (gcur), so edataB indices stay < E_total even though edataA uses
// padded coordinates. Emits offsets + degf + edges in CSR order.
// ---------------------------------------------------------------------------
__global__ __launch_bounds__(1024) void bucket_csr_kernel(
    const int* __restrict__ bucket_base, const int* __restrict__ bucket_cursor,
    const int2* __restrict__ edataA, int2* __restrict__ edataB,
    int* __restrict__ offsets, float* __restrict__ degf, int* __restrict__ gcur)
{
    int k = blockIdx.x;
    int bstart = bucket_base[k], bend = bucket_cursor[k];
    int nk = bend - bstart;
    __shared__ int h2[BWS];
    __shared__ int exc[BWS];
    __shared__ int cbase;
    int tid = threadIdx.x;
    if (tid == 0) cbase = atomicAdd(gcur, nk);   // compacted output base
    if (tid < BWS) h2[tid] = 0;
    __syncthreads();
    for (int i = bstart + tid; i < bend; i += 1024) {
        int dloc = (edataA[i].x >> 15) & 127;
        atomicAdd(&h2[dloc], 1);
    }
    __syncthreads();
    if (tid < BWS) exc[tid] = h2[tid];
    __syncthreads();
    for (int off = 1; off < BWS; off <<= 1) {
        int t = 0;
        if (tid < BWS && tid >= off) t = exc[tid - off];
        __syncthreads();
        if (tid < BWS) exc[tid] += t;
        __syncthreads();
    }
    if (tid < BWS) exc[tid] -= h2[tid];   // exclusive
    __syncthreads();
    int slot0 = k * BWS;
    if (tid < BWS && slot0 + tid < NSLOT) {
        offsets[slot0 + tid] = cbase + exc[tid];
        degf[slot0 + tid] = (float)h2[tid];
    }
    __syncthreads();
    if (tid < BWS) h2[tid] = 0;
    __syncthreads();
    for (int i = bstart + tid; i < bend; i += 1024) {
        int2 e = edataA[i];
        int dloc = (e.x >> 15) & 127;
        int rk = atomicAdd(&h2[dloc], 1);
        edataB[cbase + exc[dloc] + rk] = e;
    }
}

// ---------------------------------------------------------------------------
// Segmented reduction core (one wave per dst slot). Gather table bf16,
// accumulation fp32. 8-edge main loop = 4 gathers in flight per 32-lane
// half (latency hiding). Length comes from degf (written by bucket_csr).
// ---------------------------------------------------------------------------
__device__ __forceinline__ void reduce_one(
    const u16* __restrict__ Xb, const int* __restrict__ offsets,
    const float* __restrict__ degf, const int2* __restrict__ edata, int slot,
    int lane, float* __restrict__ S, float* __restrict__ wsumf)
{
    int start = offsets[slot];
    int end = start + (int)degf[slot];
    int half = lane >> 5;
    int q = (lane & 31) * 4;   // element offset within row (4 per lane)
    float4 acc = make_float4(0.f, 0.f, 0.f, 0.f);
    float wacc = 0.f;
    int j = start;
    for (; j + 8 <= end; j += 8) {
        int2 e0 = edata[j + half];
        int2 e1 = edata[j + 2 + half];
        int2 e2 = edata[j + 4 + half];
        int2 e3 = edata[j + 6 + half];
        ushort4 v0 = *(const ushort4*)(Xb + (size_t)(e0.x & 0x7FFF) * D + q);
        ushort4 v1 = *(const ushort4*)(Xb + (size_t)(e1.x & 0x7FFF) * D + q);
        ushort4 v2 = *(const ushort4*)(Xb + (size_t)(e2.x & 0x7FFF) * D + q);
        ushort4 v3 = *(const ushort4*)(Xb + (size_t)(e3.x & 0x7FFF) * D + q);
        float w0 = __int_as_float(e0.y), w1 = __int_as_float(e1.y);
        float w2 = __int_as_float(e2.y), w3 = __int_as_float(e3.y);
        acc.x = fmaf(w0, b2f(v0.x), acc.x); acc.y = fmaf(w0, b2f(v0.y), acc.y);
        acc.z = fmaf(w0, b2f(v0.z), acc.z); acc.w = fmaf(w0, b2f(v0.w), acc.w);
        acc.x = fmaf(w1, b2f(v1.x), acc.x); acc.y = fmaf(w1, b2f(v1.y), acc.y);
        acc.z = fmaf(w1, b2f(v1.z), acc.z); acc.w = fmaf(w1, b2f(v1.w), acc.w);
        acc.x = fmaf(w2, b2f(v2.x), acc.x); acc.y = fmaf(w2, b2f(v2.y), acc.y);
        acc.z = fmaf(w2, b2f(v2.z), acc.z); acc.w = fmaf(w2, b2f(v2.w), acc.w);
        acc.x = fmaf(w3, b2f(v3.x), acc.x); acc.y = fmaf(w3, b2f(v3.y), acc.y);
        acc.z = fmaf(w3, b2f(v3.z), acc.z); acc.w = fmaf(w3, b2f(v3.w), acc.w);
        wacc += w0 + w1 + w2 + w3;
    }
    if (j + 4 <= end) {
        int2 ea = edata[j + half];
        int2 eb = edata[j + 2 + half];
        ushort4 va = *(const ushort4*)(Xb + (size_t)(ea.x & 0x7FFF) * D + q);
        ushort4 vb = *(const ushort4*)(Xb + (size_t)(eb.x & 0x7FFF) * D + q);
        float wa = __int_as_float(ea.y);
        float wb = __int_as_float(eb.y);
        acc.x = fmaf(wa, b2f(va.x), acc.x); acc.y = fmaf(wa, b2f(va.y), acc.y);
        acc.z = fmaf(wa, b2f(va.z), acc.z); acc.w = fmaf(wa, b2f(va.w), acc.w);
        acc.x = fmaf(wb, b2f(vb.x), acc.x); acc.y = fmaf(wb, b2f(vb.y), acc.y);
        acc.z = fmaf(wb, b2f(vb.z), acc.z); acc.w = fmaf(wb, b2f(vb.w), acc.w);
        wacc += wa + wb;
        j += 4;
    }
    for (; j < end; j += 2) {
        int jj = j + half;
        int2 e = edata[jj < end ? jj : (end - 1)];
        float w = (jj < end) ? __int_as_float(e.y) : 0.f;
        ushort4 v = *(const ushort4*)(Xb + (size_t)(e.x & 0x7FFF) * D + q);
        acc.x = fmaf(w, b2f(v.x), acc.x); acc.y = fmaf(w, b2f(v.y), acc.y);
        acc.z = fmaf(w, b2f(v.z), acc.z); acc.w = fmaf(w, b2f(v.w), acc.w);
        wacc += w;
    }
    acc.x += __shfl_xor(acc.x, 32);
    acc.y += __shfl_xor(acc.y, 32);
    acc.z += __shfl_xor(acc.z, 32);
    acc.w += __shfl_xor(acc.w, 32);
    wacc  += __shfl_xor(wacc, 32);
    if (half == 0)
        *(float4*)(S + (size_t)slot * D + q) = acc;
    if (lane == 0 && wsumf) wsumf[slot] = wacc;
}

__global__ __launch_bounds__(256) void reduce_kernel(
    const u16* __restrict__ Xb, const int* __restrict__ offsets,
    const float* __restrict__ degf, const int2* __restrict__ edata,
    int slot0, int nslots, float* __restrict__ S, float* __restrict__ wsumf)
{
    int rel = blockIdx.x * 4 + (threadIdx.x >> 6);
    if (rel >= nslots) return;
    reduce_one(Xb, offsets, degf, edata, slot0 + rel, threadIdx.x & 63, S, wsumf);
}

__global__ __launch_bounds__(256) void reduce_p2_kernel(
    const u16* __restrict__ hw16, const u16* __restrict__ wtt16,
    const u16* __restrict__ wtd16, const int* __restrict__ offsets,
    const float* __restrict__ degf, const int2* __restrict__ edata,
    float* __restrict__ S, float* __restrict__ wsumf)
{
    int rel = blockIdx.x * 4 + (threadIdx.x >> 6);
    if (rel >= NP2) return;
    const u16* X;
    if (rel < NT)                 X = hw16;   // wt
    else if (rel < 2 * NT)        X = wtt16;  // tt
    else if (rel < 2 * NT + NDOC) X = hw16;   // wd
    else                          X = wtd16;  // td
    reduce_one(X, offsets, degf, edata, SEG_WT + rel, threadIdx.x & 63, S, wsumf);
}

// ---------------------------------------------------------------------------
// MFMA-based Y = X @ W (bf16 inputs, fp32 accumulate). Previous fp32 VALU mm
// was LDS-throughput-bound (~2 B LDS traffic per FLOP, 256 ds_read_b128 per
// thread). MFMA 16x16x32: 0.125 B/FLOP. Block = 4 waves x 16 rows = 64 rows.
// W^T staged in LDS as bf16, pitch 136 u16 (16B-aligned b128 frag reads,
// 2-way bank alias only). Per wave: 8 col-tiles x 4 K-steps = 32 MFMAs.
// Fragment layouts (HW-verified per guide): A[m=lane&15][k=quad*8+j],
// B[k=quad*8+j][n=lane&15], C/D col=lane&15 row=quad*4+reg.
// ---------------------------------------------------------------------------
typedef short bf16x8 __attribute__((ext_vector_type(8)));
typedef float f32x4 __attribute__((ext_vector_type(4)));
constexpr int WPITCH = 136;

__device__ __forceinline__ void stage_wt(
    const float* __restrict__ Wg, u16* Wt, int tid)
{
    for (int i = tid; i < D * D; i += 256) {
        int k = i >> 7, nn = i & 127;          // W[k][nn], coalesced global read
        Wt[nn * WPITCH + k] = f2b(Wg[i]);      // transposed LDS write (one-time)
    }
}

__device__ __forceinline__ void mfma_tile(
    const float* __restrict__ X, const u16* Wt, int arow, int n,
    int lanelo, int quad, f32x4 acc[8])
{
#pragma unroll
    for (int ct = 0; ct < 8; ++ct) {
        acc[ct][0] = 0.f; acc[ct][1] = 0.f; acc[ct][2] = 0.f; acc[ct][3] = 0.f;
    }
#pragma unroll
    for (int k0 = 0; k0 < 4; ++k0) {
        bf16x8 a;
        if (arow < n) {
            const float* ap = X + (size_t)arow * D + k0 * 32 + quad * 8;
            float4 a0 = *(const float4*)ap;
            float4 a1 = *(const float4*)(ap + 4);
            a[0] = (short)f2b(a0.x); a[1] = (short)f2b(a0.y);
            a[2] = (short)f2b(a0.z); a[3] = (short)f2b(a0.w);
            a[4] = (short)f2b(a1.x); a[5] = (short)f2b(a1.y);
            a[6] = (short)f2b(a1.z); a[7] = (short)f2b(a1.w);
        } else {
#pragma unroll
            for (int j = 0; j < 8; ++j) a[j] = 0;
        }
#pragma unroll
        for (int ct = 0; ct < 8; ++ct) {
            bf16x8 b = *(const bf16x8*)&Wt[(ct * 16 + lanelo) * WPITCH
                                           + k0 * 32 + quad * 8];
            acc[ct] = __builtin_amdgcn_mfma_f32_16x16x32_bf16(a, b, acc[ct], 0, 0, 0);
        }
    }
}

__global__ __launch_bounds__(256) void mfma_mm_kernel(
    const float* __restrict__ X, const float* __restrict__ Wg,
    const float* __restrict__ deg, const float* __restrict__ wsum,
    const float* __restrict__ bias,
    const float* __restrict__ T, const float* __restrict__ degT,
    float* __restrict__ Y, u16* __restrict__ Yb, int n)
{
    __shared__ u16 Wt[D * WPITCH];
    int tid = threadIdx.x;
    stage_wt(Wg, Wt, tid);
    __syncthreads();
    int wv = tid >> 6, lane = tid & 63;
    int lanelo = lane & 15, quad = lane >> 4;
    int rowbase = blockIdx.x * 64 + wv * 16;
    f32x4 acc[8];
    mfma_tile(X, Wt, rowbase + lanelo, n, lanelo, quad, acc);

    int rbase = rowbase + quad * 4;
#pragma unroll
    for (int r = 0; r < 4; ++r) {
        int row = rbase + r;
        if (row >= n) continue;
        float dgv = deg[row];
        float wsv = wsum ? wsum[row] : 0.f;
        float dtv = degT ? degT[row] : 0.f;
#pragma unroll
        for (int ct = 0; ct < 8; ++ct) {
            int col = ct * 16 + lanelo;
            float y = acc[ct][r];
            y = dgv > 0.f ? (y + wsv * bias[col]) / dgv : 0.f;
            if (T && dtv > 0.f) y += T[(size_t)row * D + col] / dtv;
            Y[(size_t)row * D + col] = y;
            if (Yb) Yb[(size_t)row * D + col] = f2b(y);
        }
    }
}

// 4 simultaneous [NT x 128] @ [128 x 128] products (blockIdx.y selects W/P).
struct MM4 { const float* W[4]; float* P[4]; };
__global__ __launch_bounds__(256) void mfma_mm4_kernel(
    const float* __restrict__ X, MM4 p, int n)
{
    __shared__ u16 Wt[D * WPITCH];
    int tid = threadIdx.x;
    stage_wt(p.W[blockIdx.y], Wt, tid);
    __syncthreads();
    int wv = tid >> 6, lane = tid & 63;
    int lanelo = lane & 15, quad = lane >> 4;
    int rowbase = blockIdx.x * 64 + wv * 16;
    f32x4 acc[8];
    mfma_tile(X, Wt, rowbase + lanelo, n, lanelo, quad, acc);
    float* Y = p.P[blockIdx.y];
    int rbase = rowbase + quad * 4;
#pragma unroll
    for (int r = 0; r < 4; ++r) {
        int row = rbase + r;
        if (row >= n) continue;
#pragma unroll
        for (int ct = 0; ct < 8; ++ct)
            Y[(size_t)row * D + ct * 16 + lanelo] = acc[ct][r];
    }
}

// ---------------------------------------------------------------------------
// Wh_td = P_td + b_td + causal*Pc - rm_td*Pn ; same for tt. Emits bf16.
// ---------------------------------------------------------------------------
__global__ __launch_bounds__(256) void combine_topic_kernel(
    const float* __restrict__ P_td, const float* __restrict__ P_tt,
    const float* __restrict__ Pc, const float* __restrict__ Pn,
    const float* __restrict__ effect, const float* __restrict__ bern_td,
    const float* __restrict__ bern_tt,
    const float* __restrict__ b_td, const float* __restrict__ b_tt,
    u16* __restrict__ wtd16, u16* __restrict__ wtt16)
{
    int i = blockIdx.x * 256 + threadIdx.x;
    if (i >= NT * D) return;
    int row = i >> 7;
    int col = i & (D - 1);
    float eff = effect[row];
    float causal = (eff != 0.f) ? 1.f : 0.f;
    float zero = (eff == 0.f) ? 1.f : 0.f;
    float rmtd = bern_td[row] * zero;
    float rmtt = bern_tt[row] * zero;
    float pc = Pc[i];
    float pn = Pn[i];
    wtd16[i] = f2b(P_td[i] + b_td[col] + causal * pc - rmtd * pn);
    wtt16[i] = f2b(P_tt[i] + b_tt[col] + causal * pc - rmtt * pn);
}

extern "C" void kernel_launch(void* const* d_in, const int* in_sizes, int n_in,
                              void* d_out, int out_size, void* d_ws, size_t ws_size,
                              hipStream_t stream)
{
    const float* feat_word  = (const float*)d_in[0];
    const float* feat_topic = (const float*)d_in[1];
    const float* effect     = (const float*)d_in[2];
    const float* bern_td    = (const float*)d_in[3];
    const float* bern_tt    = (const float*)d_in[4];
    const int*   src_ww = (const int*)d_in[5];
    const int*   dst_ww = (const int*)d_in[6];
    const float* w_ww   = (const float*)d_in[7];
    const int*   src_wt = (const int*)d_in[8];
    const int*   dst_wt = (const int*)d_in[9];
    const float* w_wt   = (const float*)d_in[10];
    const int*   src_wd = (const int*)d_in[11];
    const int*   dst_wd = (const int*)d_in[12];
    const float* w_wd   = (const float*)d_in[13];
    const int*   src_td = (const int*)d_in[14];
    const int*   dst_td = (const int*)d_in[15];
    const float* w_td   = (const float*)d_in[16];
    const int*   src_tt = (const int*)d_in[17];
    const int*   dst_tt = (const int*)d_in[18];
    const float* w_tt   = (const float*)d_in[19];
    const float* W_ww = (const float*)d_in[20];
    const float* b_ww = (const float*)d_in[21];
    const float* W_wt = (const float*)d_in[22];
    const float* b_wt = (const float*)d_in[23];
    const float* W_wd = (const float*)d_in[24];
    const float* b_wd = (const float*)d_in[25];
    const float* W_td = (const float*)d_in[26];
    const float* b_td = (const float*)d_in[27];
    const float* W_tt = (const float*)d_in[28];
    const float* b_tt = (const float*)d_in[29];
    const float* W_causal = (const float*)d_in[30];
    const float* W_noise  = (const float*)d_in[31];

    const int E_ww = in_sizes[5];
    const int E_wt = in_sizes[8];
    const int E_wd = in_sizes[11];
    const int E_td = in_sizes[14];
    const int E_tt = in_sizes[17];
    const int E_total = E_ww + E_wt + E_wd + E_td + E_tt;
    // padded edataA capacity: sum of per-bucket caps <= 1.5*E_total + 128*NBKT
    const long long capA = (long long)(1.5 * E_total) + 128LL * NBKT + 256;

    // ---- workspace layout (4-byte units; dedicated regions, NO overlays) ----
    float* ws = (float*)d_ws;
    float* S      = ws; ws += (long long)NSLOT * D;
    float* degf   = ws; ws += NSLOT;
    float* wsumf  = ws; ws += NSLOT;
    int*   offsets      = (int*)ws; ws += NSLOT + 1;
    int*   bucket_base  = (int*)ws; ws += NBKT + 1;
    int*   bucket_cursor= (int*)ws; ws += NBKT;
    int*   gcur         = (int*)ws; ws += 1;
    ws += ((size_t)(ws - (float*)d_ws) & 1);          // 8B align
    int2*  edataB   = (int2*)ws; ws += (long long)2 * E_total;   // compact coords
    int2*  edataA   = (int2*)ws; ws += 2 * capA;                 // padded coords
    float* P_td  = ws; ws += (long long)NT * D;
    float* P_tt  = ws; ws += (long long)NT * D;
    float* Pc    = ws; ws += (long long)NT * D;
    float* Pn    = ws; ws += (long long)NT * D;
    u16*   fw16     = (u16*)ws;  ws += (long long)NW * D / 2;   // bf16 feat_word
    u16*   hw16     = (u16*)ws;  ws += (long long)NW * D / 2;   // bf16 h_word
    u16*   wtd16    = (u16*)ws;  ws += (long long)NT * D / 2;
    u16*   wtt16    = (u16*)ws;  ws += (long long)NT * D / 2;

    float* h_word  = (float*)d_out;
    float* h_topic = h_word + (long long)NW * D;
    float* h_doc   = h_topic + (long long)NT * D;

    auto nb = [](long long n) { return (unsigned)((n + 255) / 256); };

    Rels R;
    R.r[0] = { src_ww, dst_ww, w_ww, 0, SEG_WW };
    R.r[1] = { src_wt, dst_wt, w_wt, E_ww, SEG_WT };
    R.r[2] = { src_tt, dst_tt, w_tt, E_ww + E_wt, SEG_TT };
    R.r[3] = { src_wd, dst_wd, w_wd, E_ww + E_wt + E_tt, SEG_WD };
    R.r[4] = { src_td, dst_td, w_td, E_ww + E_wt + E_tt + E_wd, SEG_TD };

    // ---- bf16 gather table for feat_word ----
    f2b_kernel<<<nb((long long)NW * D / 4), 256, 0, stream>>>(
        feat_word, fw16, NW * D / 4);

    // ---- Topic-side precompute: 4-way parallel MFMA matmuls + combine ----
    MM4 m4;
    m4.W[0] = W_td; m4.W[1] = W_tt; m4.W[2] = W_causal; m4.W[3] = W_noise;
    m4.P[0] = P_td; m4.P[1] = P_tt; m4.P[2] = Pc;       m4.P[3] = Pn;
    mfma_mm4_kernel<<<dim3((NT + 63) / 64, 4), 256, 0, stream>>>(feat_topic, m4, NT);
    combine_topic_kernel<<<nb(NT * D), 256, 0, stream>>>(
        P_td, P_tt, Pc, Pn, effect, bern_td, bern_tt, b_td, b_tt, wtd16, wtt16);

    // ---- CSR build: analytic caps/scan -> partition -> per-bucket CSR ----
    cap_scan_kernel<<<1, 256, 0, stream>>>(
        (float)E_ww / NW, (float)E_wt / NT, (float)E_tt / NT,
        (float)E_wd / NDOC, (float)E_td / NDOC, bucket_base, bucket_cursor, gcur);
    unsigned npb = (unsigned)((E_total + EPB - 1) / EPB);
    partition_kernel<<<npb, 256, 0, stream>>>(R, E_total, bucket_cursor, edataA);
    bucket_csr_kernel<<<NBKT, 1024, 0, stream>>>(
        bucket_base, bucket_cursor, edataA, edataB, offsets, degf, gcur);

    // ---- Phase 1: ww reduce + word projection (fp32 out + bf16 mirror) ----
    reduce_kernel<<<(NW + 3) / 4, 256, 0, stream>>>(
        fw16, offsets, degf, edataB, SEG_WW, NW, S, wsumf);
    mfma_mm_kernel<<<(NW + 63) / 64, 256, 0, stream>>>(
        S + (long long)SEG_WW * D, W_ww, degf + SEG_WW, wsumf + SEG_WW, b_ww,
        nullptr, nullptr, h_word, hw16, NW);

    // ---- Phase 2: merged reduce over wt/tt/wd/td ----
    reduce_p2_kernel<<<(NP2 + 3) / 4, 256, 0, stream>>>(
        hw16, wtt16, wtd16, offsets, degf, edataB, S, wsumf);

    // ---- Final projections + cross-relation sums ----
    mfma_mm_kernel<<<(NT + 63) / 64, 256, 0, stream>>>(
        S + (long long)SEG_WT * D, W_wt, degf + SEG_WT, wsumf + SEG_WT, b_wt,
        S + (long long)SEG_TT * D, degf + SEG_TT, h_topic, nullptr, NT);
    mfma_mm_kernel<<<(NDOC + 63) / 64, 256, 0, stream>>>(
        S + (long long)SEG_WD * D, W_wd, degf + SEG_WD, wsumf + SEG_WD, b_wd,
        S + (long long)SEG_TD * D, degf + SEG_TD, h_doc, nullptr, NDOC);

    (void)n_in; (void)in_sizes; (void)out_size; (void)ws_size;
}

// Round 12
// 307.390 us; speedup vs baseline: 1.2508x; 1.0850x over previous
//
#include <hip/hip_runtime.h>

#define D 128
typedef unsigned short u16;
constexpr int NW = 30000;
constexpr int NT = 2000;
constexpr int NDOC = 20000;
constexpr int NSLOT = NW + NT + NT + NDOC + NDOC;   // 74000 destination slots
constexpr int SEG_WW = 0;
constexpr int SEG_WT = NW;                 // 30000
constexpr int SEG_TT = NW + NT;            // 32000
constexpr int SEG_WD = NW + 2 * NT;        // 34000
constexpr int SEG_TD = NW + 2 * NT + NDOC; // 54000
constexpr int NP2 = NT + NT + NDOC + NDOC; // 44000 phase-2 slots

constexpr int BWS = 128;                    // slots per bucket (pow2: slot>>7)
constexpr int NBKT = (NSLOT + BWS - 1) / BWS;  // 579
constexpr int EPB = 2048;                   // edges per partition block (grid ~704)

struct RelDesc { const int* src; const int* dst; const float* w; int e0; int seg; };
struct Rels { RelDesc r[5]; };

__device__ __forceinline__ void resolve_rel(const Rels& R, int e,
    const int*& srcp, const int*& dstp, const float*& wp, int& le, int& seg)
{
    int k;
    if (e < R.r[1].e0) k = 0;
    else if (e < R.r[2].e0) k = 1;
    else if (e < R.r[3].e0) k = 2;
    else if (e < R.r[4].e0) k = 3;
    else k = 4;
    srcp = R.r[k].src; dstp = R.r[k].dst; wp = R.r[k].w;
    le = e - R.r[k].e0; seg = R.r[k].seg;
}

__device__ __forceinline__ float b2f(u16 h)
{
    return __uint_as_float(((unsigned)h) << 16);
}
__device__ __forceinline__ u16 f2b(float f)   // round-to-nearest-even
{
    unsigned u = __float_as_uint(f);
    return (u16)((u + 0x7FFF + ((u >> 16) & 1)) >> 16);
}

// ---------------------------------------------------------------------------
// fp32 -> bf16 table conversion (feat_word): 4 elements per thread.
// ---------------------------------------------------------------------------
__global__ __launch_bounds__(256) void f2b_kernel(
    const float* __restrict__ X, u16* __restrict__ Y, int n4)
{
    int i = blockIdx.x * 256 + threadIdx.x;
    if (i >= n4) return;
    float4 v = ((const float4*)X)[i];
    ushort4 o;
    o.x = f2b(v.x); o.y = f2b(v.y); o.z = f2b(v.z); o.w = f2b(v.w);
    ((ushort4*)Y)[i] = o;
}

// ---------------------------------------------------------------------------
// Analytic bucket capacities + prefix scan -> bucket_base/cursor (PADDED
// coordinates for edataA, which is sized for them). Zeroes the compaction
// cursor. cap_k = 1.5 * expected + 128 (many-sigma margin, uniform dst).
// ---------------------------------------------------------------------------
__global__ __launch_bounds__(256) void cap_scan_kernel(
    float m_ww, float m_wt, float m_tt, float m_wd, float m_td,
    int* __restrict__ bucket_base, int* __restrict__ bucket_cursor,
    int* __restrict__ gcur)
{
    __shared__ int chs[256];
    __shared__ int vals[256 * 3];
    int tid = threadIdx.x;
    if (tid == 0) *gcur = 0;
    int s = 0;
    for (int j = 0; j < 3; ++j) {
        int k = tid * 3 + j;
        int c = 0;
        if (k < NBKT) {
            int a = k * BWS, b = min(a + BWS, NSLOT);
            auto ov = [&](int lo, int hi) {
                return (float)max(0, min(b, hi) - max(a, lo));
            };
            float ex = ov(SEG_WW, SEG_WT) * m_ww + ov(SEG_WT, SEG_TT) * m_wt
                     + ov(SEG_TT, SEG_WD) * m_tt + ov(SEG_WD, SEG_TD) * m_wd
                     + ov(SEG_TD, NSLOT) * m_td;
            c = (int)(ex * 1.5f) + 128;
        }
        vals[tid * 3 + j] = c;
        s += c;
    }
    chs[tid] = s;
    __syncthreads();
    for (int off = 1; off < 256; off <<= 1) {
        int t = (tid >= off) ? chs[tid - off] : 0;
        __syncthreads();
        chs[tid] += t;
        __syncthreads();
    }
    int run = (tid == 0) ? 0 : chs[tid - 1];
    for (int j = 0; j < 3; ++j) {
        int k = tid * 3 + j;
        if (k < NBKT) {
            bucket_base[k] = run;
            bucket_cursor[k] = run;
            run += vals[tid * 3 + j];
        }
    }
}

// ---------------------------------------------------------------------------
// A3: partition edges into capacity-padded bucket regions of edataA. One
// global atomic per (block,bucket); writes are contiguous chunks.
// Entry: x = src | (dloc<<15), y = w bits.
// ---------------------------------------------------------------------------
__global__ __launch_bounds__(256) void partition_kernel(
    Rels R, int Etot, int* __restrict__ bucket_cursor, int2* __restrict__ edataA)
{
    __shared__ int hist[NBKT];
    __shared__ int baseL[NBKT];
    __shared__ u16 bkt[EPB];
    __shared__ unsigned char dl[EPB];
    int tid = threadIdx.x;
    for (int i = tid; i < NBKT; i += 256) hist[i] = 0;
    __syncthreads();
    int base_e = blockIdx.x * EPB;
    for (int r = 0; r < EPB / 256; ++r) {
        int idx = r * 256 + tid;
        int e = base_e + idx;
        if (e < Etot) {
            const int *srcp, *dstp; const float* wp; int le, seg;
            resolve_rel(R, e, srcp, dstp, wp, le, seg);
            int g = seg + dstp[le];
            bkt[idx] = (u16)(g >> 7);
            dl[idx] = (unsigned char)(g & 127);
            atomicAdd(&hist[g >> 7], 1);
        } else {
            bkt[idx] = 0xFFFF;
        }
    }
    __syncthreads();
    for (int i = tid; i < NBKT; i += 256)
        baseL[i] = hist[i] ? atomicAdd(&bucket_cursor[i], hist[i]) : 0;
    __syncthreads();
    for (int i = tid; i < NBKT; i += 256) hist[i] = 0;
    __syncthreads();
    for (int r = 0; r < EPB / 256; ++r) {
        int idx = r * 256 + tid;
        int e = base_e + idx;
        if (e < Etot) {
            const int *srcp, *dstp; const float* wp; int le, seg;
            resolve_rel(R, e, srcp, dstp, wp, le, seg);
            int b = bkt[idx];
            int rk = atomicAdd(&hist[b], 1);
            edataA[baseL[b] + rk] =
                make_int2(srcp[le] | ((int)dl[idx] << 15), __float_as_int(wp[le]));
        }
    }
}

// ---------------------------------------------------------------------------
// B: one block (1024 threads) per bucket. LDS histogram over 128 slots ->
// scan -> COMPACT: claim nk contiguous entries of edataB via one global
// atomic (gcur), so edataB indices stay < E_total even though edataA uses
// padded coordinates. Emits offsets + degf + edges in CSR order.
// ---------------------------------------------------------------------------
__global__ __launch_bounds__(1024) void bucket_csr_kernel(
    const int* __restrict__ bucket_base, const int* __restrict__ bucket_cursor,
    const int2* __restrict__ edataA, int2* __restrict__ edataB,
    int* __restrict__ offsets, float* __restrict__ degf, int* __restrict__ gcur)
{
    int k = blockIdx.x;
    int bstart = bucket_base[k], bend = bucket_cursor[k];
    int nk = bend - bstart;
    __shared__ int h2[BWS];
    __shared__ int exc[BWS];
    __shared__ int cbase;
    int tid = threadIdx.x;
    if (tid == 0) cbase = atomicAdd(gcur, nk);   // compacted output base
    if (tid < BWS) h2[tid] = 0;
    __syncthreads();
    for (int i = bstart + tid; i < bend; i += 1024) {
        int dloc = (edataA[i].x >> 15) & 127;
        atomicAdd(&h2[dloc], 1);
    }
    __syncthreads();
    if (tid < BWS) exc[tid] = h2[tid];
    __syncthreads();
    for (int off = 1; off < BWS; off <<= 1) {
        int t = 0;
        if (tid < BWS && tid >= off) t = exc[tid - off];
        __syncthreads();
        if (tid < BWS) exc[tid] += t;
        __syncthreads();
    }
    if (tid < BWS) exc[tid] -= h2[tid];   // exclusive
    __syncthreads();
    int slot0 = k * BWS;
    if (tid < BWS && slot0 + tid < NSLOT) {
        offsets[slot0 + tid] = cbase + exc[tid];
        degf[slot0 + tid] = (float)h2[tid];
    }
    __syncthreads();
    if (tid < BWS) h2[tid] = 0;
    __syncthreads();
    for (int i = bstart + tid; i < bend; i += 1024) {
        int2 e = edataA[i];
        int dloc = (e.x >> 15) & 127;
        int rk = atomicAdd(&h2[dloc], 1);
        edataB[cbase + exc[dloc] + rk] = e;
    }
}

// ---------------------------------------------------------------------------
// Segmented reduction core (one wave per dst slot). Gather table bf16,
// accumulation fp32. 16-edge main loop = 8 gathers in flight per 32-lane
// half (reduces were latency-bound at 4 in flight: need ~13 waves/SIMD to
// hide ~900cyc at 4, cap is 8 — doubling MLP halves the stall).
// ---------------------------------------------------------------------------
__device__ __forceinline__ void reduce_one(
    const u16* __restrict__ Xb, const int* __restrict__ offsets,
    const float* __restrict__ degf, const int2* __restrict__ edata, int slot,
    int lane, float* __restrict__ S, float* __restrict__ wsumf)
{
    int start = offsets[slot];
    int end = start + (int)degf[slot];
    int half = lane >> 5;
    int q = (lane & 31) * 4;   // element offset within row (4 per lane)
    float4 acc = make_float4(0.f, 0.f, 0.f, 0.f);
    float wacc = 0.f;
    int j = start;
    for (; j + 16 <= end; j += 16) {       // 8 gathers in flight per lane
        int2 ee[8];
        ushort4 vv[8];
#pragma unroll
        for (int t = 0; t < 8; ++t) ee[t] = edata[j + 2 * t + half];
#pragma unroll
        for (int t = 0; t < 8; ++t)
            vv[t] = *(const ushort4*)(Xb + (size_t)(ee[t].x & 0x7FFF) * D + q);
#pragma unroll
        for (int t = 0; t < 8; ++t) {
            float w = __int_as_float(ee[t].y);
            acc.x = fmaf(w, b2f(vv[t].x), acc.x);
            acc.y = fmaf(w, b2f(vv[t].y), acc.y);
            acc.z = fmaf(w, b2f(vv[t].z), acc.z);
            acc.w = fmaf(w, b2f(vv[t].w), acc.w);
            wacc += w;
        }
    }
    if (j + 8 <= end) {
        int2 ee[4];
        ushort4 vv[4];
#pragma unroll
        for (int t = 0; t < 4; ++t) ee[t] = edata[j + 2 * t + half];
#pragma unroll
        for (int t = 0; t < 4; ++t)
            vv[t] = *(const ushort4*)(Xb + (size_t)(ee[t].x & 0x7FFF) * D + q);
#pragma unroll
        for (int t = 0; t < 4; ++t) {
            float w = __int_as_float(ee[t].y);
            acc.x = fmaf(w, b2f(vv[t].x), acc.x);
            acc.y = fmaf(w, b2f(vv[t].y), acc.y);
            acc.z = fmaf(w, b2f(vv[t].z), acc.z);
            acc.w = fmaf(w, b2f(vv[t].w), acc.w);
            wacc += w;
        }
        j += 8;
    }
    if (j + 4 <= end) {
        int2 ea = edata[j + half];
        int2 eb = edata[j + 2 + half];
        ushort4 va = *(const ushort4*)(Xb + (size_t)(ea.x & 0x7FFF) * D + q);
        ushort4 vb = *(const ushort4*)(Xb + (size_t)(eb.x & 0x7FFF) * D + q);
        float wa = __int_as_float(ea.y);
        float wb = __int_as_float(eb.y);
        acc.x = fmaf(wa, b2f(va.x), acc.x); acc.y = fmaf(wa, b2f(va.y), acc.y);
        acc.z = fmaf(wa, b2f(va.z), acc.z); acc.w = fmaf(wa, b2f(va.w), acc.w);
        acc.x = fmaf(wb, b2f(vb.x), acc.x); acc.y = fmaf(wb, b2f(vb.y), acc.y);
        acc.z = fmaf(wb, b2f(vb.z), acc.z); acc.w = fmaf(wb, b2f(vb.w), acc.w);
        wacc += wa + wb;
        j += 4;
    }
    for (; j < end; j += 2) {
        int jj = j + half;
        int2 e = edata[jj < end ? jj : (end - 1)];
        float w = (jj < end) ? __int_as_float(e.y) : 0.f;
        ushort4 v = *(const ushort4*)(Xb + (size_t)(e.x & 0x7FFF) * D + q);
        acc.x = fmaf(w, b2f(v.x), acc.x); acc.y = fmaf(w, b2f(v.y), acc.y);
        acc.z = fmaf(w, b2f(v.z), acc.z); acc.w = fmaf(w, b2f(v.w), acc.w);
        wacc += w;
    }
    acc.x += __shfl_xor(acc.x, 32);
    acc.y += __shfl_xor(acc.y, 32);
    acc.z += __shfl_xor(acc.z, 32);
    acc.w += __shfl_xor(acc.w, 32);
    wacc  += __shfl_xor(wacc, 32);
    if (half == 0)
        *(float4*)(S + (size_t)slot * D + q) = acc;
    if (lane == 0 && wsumf) wsumf[slot] = wacc;
}

__global__ __launch_bounds__(256) void reduce_kernel(
    const u16* __restrict__ Xb, const int* __restrict__ offsets,
    const float* __restrict__ degf, const int2* __restrict__ edata,
    int slot0, int nslots, float* __restrict__ S, float* __restrict__ wsumf)
{
    int rel = blockIdx.x * 4 + (threadIdx.x >> 6);
    if (rel >= nslots) return;
    reduce_one(Xb, offsets, degf, edata, slot0 + rel, threadIdx.x & 63, S, wsumf);
}

__global__ __launch_bounds__(256) void reduce_p2_kernel(
    const u16* __restrict__ hw16, const u16* __restrict__ wtt16,
    const u16* __restrict__ wtd16, const int* __restrict__ offsets,
    const float* __restrict__ degf, const int2* __restrict__ edata,
    float* __restrict__ S, float* __restrict__ wsumf)
{
    int rel = blockIdx.x * 4 + (threadIdx.x >> 6);
    if (rel >= NP2) return;
    const u16* X;
    if (rel < NT)                 X = hw16;   // wt
    else if (rel < 2 * NT)        X = wtt16;  // tt
    else if (rel < 2 * NT + NDOC) X = hw16;   // wd
    else                          X = wtd16;  // td
    reduce_one(X, offsets, degf, edata, SEG_WT + rel, threadIdx.x & 63, S, wsumf);
}

// ---------------------------------------------------------------------------
// MFMA-based Y = X @ W (bf16 inputs, fp32 accumulate). Block = 4 waves x 16
// rows. W^T staged in LDS as bf16, pitch 136 u16. Per wave: 8 col-tiles x 4
// K-steps = 32 MFMAs. Fragment layouts per HW-verified guide mappings.
// ---------------------------------------------------------------------------
typedef short bf16x8 __attribute__((ext_vector_type(8)));
typedef float f32x4 __attribute__((ext_vector_type(4)));
constexpr int WPITCH = 136;

__device__ __forceinline__ void stage_wt(
    const float* __restrict__ Wg, u16* Wt, int tid)
{
    for (int i = tid; i < D * D; i += 256) {
        int k = i >> 7, nn = i & 127;          // W[k][nn], coalesced global read
        Wt[nn * WPITCH + k] = f2b(Wg[i]);      // transposed LDS write (one-time)
    }
}

__device__ __forceinline__ void mfma_tile(
    const float* __restrict__ X, const u16* Wt, int arow, int n,
    int lanelo, int quad, f32x4 acc[8])
{
#pragma unroll
    for (int ct = 0; ct < 8; ++ct) {
        acc[ct][0] = 0.f; acc[ct][1] = 0.f; acc[ct][2] = 0.f; acc[ct][3] = 0.f;
    }
#pragma unroll
    for (int k0 = 0; k0 < 4; ++k0) {
        bf16x8 a;
        if (arow < n) {
            const float* ap = X + (size_t)arow * D + k0 * 32 + quad * 8;
            float4 a0 = *(const float4*)ap;
            float4 a1 = *(const float4*)(ap + 4);
            a[0] = (short)f2b(a0.x); a[1] = (short)f2b(a0.y);
            a[2] = (short)f2b(a0.z); a[3] = (short)f2b(a0.w);
            a[4] = (short)f2b(a1.x); a[5] = (short)f2b(a1.y);
            a[6] = (short)f2b(a1.z); a[7] = (short)f2b(a1.w);
        } else {
#pragma unroll
            for (int j = 0; j < 8; ++j) a[j] = 0;
        }
#pragma unroll
        for (int ct = 0; ct < 8; ++ct) {
            bf16x8 b = *(const bf16x8*)&Wt[(ct * 16 + lanelo) * WPITCH
                                           + k0 * 32 + quad * 8];
            acc[ct] = __builtin_amdgcn_mfma_f32_16x16x32_bf16(a, b, acc[ct], 0, 0, 0);
        }
    }
}

__device__ __forceinline__ void mfma_mm_body(
    const float* __restrict__ X, const float* __restrict__ Wg,
    const float* __restrict__ deg, const float* __restrict__ wsum,
    const float* __restrict__ bias,
    const float* __restrict__ T, const float* __restrict__ degT,
    float* __restrict__ Y, u16* __restrict__ Yb, int n,
    u16* Wt, int tid, int bx)
{
    stage_wt(Wg, Wt, tid);
    __syncthreads();
    int wv = tid >> 6, lane = tid & 63;
    int lanelo = lane & 15, quad = lane >> 4;
    int rowbase = bx * 64 + wv * 16;
    f32x4 acc[8];
    mfma_tile(X, Wt, rowbase + lanelo, n, lanelo, quad, acc);

    int rbase = rowbase + quad * 4;
#pragma unroll
    for (int r = 0; r < 4; ++r) {
        int row = rbase + r;
        if (row >= n) continue;
        float dgv = deg[row];
        float wsv = wsum ? wsum[row] : 0.f;
        float dtv = degT ? degT[row] : 0.f;
#pragma unroll
        for (int ct = 0; ct < 8; ++ct) {
            int col = ct * 16 + lanelo;
            float y = acc[ct][r];
            y = dgv > 0.f ? (y + wsv * bias[col]) / dgv : 0.f;
            if (T && dtv > 0.f) y += T[(size_t)row * D + col] / dtv;
            Y[(size_t)row * D + col] = y;
            if (Yb) Yb[(size_t)row * D + col] = f2b(y);
        }
    }
}

__global__ __launch_bounds__(256) void mfma_mm_kernel(
    const float* __restrict__ X, const float* __restrict__ Wg,
    const float* __restrict__ deg, const float* __restrict__ wsum,
    const float* __restrict__ bias,
    const float* __restrict__ T, const float* __restrict__ degT,
    float* __restrict__ Y, u16* __restrict__ Yb, int n)
{
    __shared__ u16 Wt[D * WPITCH];
    mfma_mm_body(X, Wg, deg, wsum, bias, T, degT, Y, Yb, n,
                 Wt, threadIdx.x, blockIdx.x);
}

// Final projections merged: blocks [0,nb0) -> topic, [nb0,..) -> doc.
struct MMF {
    const float* X[2]; const float* W[2]; const float* deg[2];
    const float* wsum[2]; const float* bias[2];
    const float* T[2]; const float* degT[2];
    float* Y[2]; int n[2]; int nb0;
};
__global__ __launch_bounds__(256) void mfma_mm2_kernel(MMF p)
{
    __shared__ u16 Wt[D * WPITCH];
    int which = (int)(blockIdx.x >= (unsigned)p.nb0);
    int bx = which ? (int)blockIdx.x - p.nb0 : (int)blockIdx.x;
    mfma_mm_body(p.X[which], p.W[which], p.deg[which], p.wsum[which],
                 p.bias[which], p.T[which], p.degT[which], p.Y[which],
                 nullptr, p.n[which], Wt, threadIdx.x, bx);
}

// 4 simultaneous [NT x 128] @ [128 x 128] products (blockIdx.y selects W/P).
struct MM4 { const float* W[4]; float* P[4]; };
__global__ __launch_bounds__(256) void mfma_mm4_kernel(
    const float* __restrict__ X, MM4 p, int n)
{
    __shared__ u16 Wt[D * WPITCH];
    int tid = threadIdx.x;
    stage_wt(p.W[blockIdx.y], Wt, tid);
    __syncthreads();
    int wv = tid >> 6, lane = tid & 63;
    int lanelo = lane & 15, quad = lane >> 4;
    int rowbase = blockIdx.x * 64 + wv * 16;
    f32x4 acc[8];
    mfma_tile(X, Wt, rowbase + lanelo, n, lanelo, quad, acc);
    float* Y = p.P[blockIdx.y];
    int rbase = rowbase + quad * 4;
#pragma unroll
    for (int r = 0; r < 4; ++r) {
        int row = rbase + r;
        if (row >= n) continue;
#pragma unroll
        for (int ct = 0; ct < 8; ++ct)
            Y[(size_t)row * D + ct * 16 + lanelo] = acc[ct][r];
    }
}

// ---------------------------------------------------------------------------
// Wh_td = P_td + b_td + causal*Pc - rm_td*Pn ; same for tt. Emits bf16.
// ---------------------------------------------------------------------------
__global__ __launch_bounds__(256) void combine_topic_kernel(
    const float* __restrict__ P_td, const float* __restrict__ P_tt,
    const float* __restrict__ Pc, const float* __restrict__ Pn,
    const float* __restrict__ effect, const float* __restrict__ bern_td,
    const float* __restrict__ bern_tt,
    const float* __restrict__ b_td, const float* __restrict__ b_tt,
    u16* __restrict__ wtd16, u16* __restrict__ wtt16)
{
    int i = blockIdx.x * 256 + threadIdx.x;
    if (i >= NT * D) return;
    int row = i >> 7;
    int col = i & (D - 1);
    float eff = effect[row];
    float causal = (eff != 0.f) ? 1.f : 0.f;
    float zero = (eff == 0.f) ? 1.f : 0.f;
    float rmtd = bern_td[row] * zero;
    float rmtt = bern_tt[row] * zero;
    float pc = Pc[i];
    float pn = Pn[i];
    wtd16[i] = f2b(P_td[i] + b_td[col] + causal * pc - rmtd * pn);
    wtt16[i] = f2b(P_tt[i] + b_tt[col] + causal * pc - rmtt * pn);
}

extern "C" void kernel_launch(void* const* d_in, const int* in_sizes, int n_in,
                              void* d_out, int out_size, void* d_ws, size_t ws_size,
                              hipStream_t stream)
{
    const float* feat_word  = (const float*)d_in[0];
    const float* feat_topic = (const float*)d_in[1];
    const float* effect     = (const float*)d_in[2];
    const float* bern_td    = (const float*)d_in[3];
    const float* bern_tt    = (const float*)d_in[4];
    const int*   src_ww = (const int*)d_in[5];
    const int*   dst_ww = (const int*)d_in[6];
    const float* w_ww   = (const float*)d_in[7];
    const int*   src_wt = (const int*)d_in[8];
    const int*   dst_wt = (const int*)d_in[9];
    const float* w_wt   = (const float*)d_in[10];
    const int*   src_wd = (const int*)d_in[11];
    const int*   dst_wd = (const int*)d_in[12];
    const float* w_wd   = (const float*)d_in[13];
    const int*   src_td = (const int*)d_in[14];
    const int*   dst_td = (const int*)d_in[15];
    const float* w_td   = (const float*)d_in[16];
    const int*   src_tt = (const int*)d_in[17];
    const int*   dst_tt = (const int*)d_in[18];
    const float* w_tt   = (const float*)d_in[19];
    const float* W_ww = (const float*)d_in[20];
    const float* b_ww = (const float*)d_in[21];
    const float* W_wt = (const float*)d_in[22];
    const float* b_wt = (const float*)d_in[23];
    const float* W_wd = (const float*)d_in[24];
    const float* b_wd = (const float*)d_in[25];
    const float* W_td = (const float*)d_in[26];
    const float* b_td = (const float*)d_in[27];
    const float* W_tt = (const float*)d_in[28];
    const float* b_tt = (const float*)d_in[29];
    const float* W_causal = (const float*)d_in[30];
    const float* W_noise  = (const float*)d_in[31];

    const int E_ww = in_sizes[5];
    const int E_wt = in_sizes[8];
    const int E_wd = in_sizes[11];
    const int E_td = in_sizes[14];
    const int E_tt = in_sizes[17];
    const int E_total = E_ww + E_wt + E_wd + E_td + E_tt;
    // padded edataA capacity: sum of per-bucket caps <= 1.5*E_total + 128*NBKT
    const long long capA = (long long)(1.5 * E_total) + 128LL * NBKT + 256;

    // ---- workspace layout (4-byte units; dedicated regions, NO overlays) ----
    float* ws = (float*)d_ws;
    float* S      = ws; ws += (long long)NSLOT * D;
    float* degf   = ws; ws += NSLOT;
    float* wsumf  = ws; ws += NSLOT;
    int*   offsets      = (int*)ws; ws += NSLOT + 1;
    int*   bucket_base  = (int*)ws; ws += NBKT + 1;
    int*   bucket_cursor= (int*)ws; ws += NBKT;
    int*   gcur         = (int*)ws; ws += 1;
    ws += ((size_t)(ws - (float*)d_ws) & 1);          // 8B align
    int2*  edataB   = (int2*)ws; ws += (long long)2 * E_total;   // compact coords
    int2*  edataA   = (int2*)ws; ws += 2 * capA;                 // padded coords
    float* P_td  = ws; ws += (long long)NT * D;
    float* P_tt  = ws; ws += (long long)NT * D;
    float* Pc    = ws; ws += (long long)NT * D;
    float* Pn    = ws; ws += (long long)NT * D;
    u16*   fw16     = (u16*)ws;  ws += (long long)NW * D / 2;   // bf16 feat_word
    u16*   hw16     = (u16*)ws;  ws += (long long)NW * D / 2;   // bf16 h_word
    u16*   wtd16    = (u16*)ws;  ws += (long long)NT * D / 2;
    u16*   wtt16    = (u16*)ws;  ws += (long long)NT * D / 2;

    float* h_word  = (float*)d_out;
    float* h_topic = h_word + (long long)NW * D;
    float* h_doc   = h_topic + (long long)NT * D;

    auto nb = [](long long n) { return (unsigned)((n + 255) / 256); };

    Rels R;
    R.r[0] = { src_ww, dst_ww, w_ww, 0, SEG_WW };
    R.r[1] = { src_wt, dst_wt, w_wt, E_ww, SEG_WT };
    R.r[2] = { src_tt, dst_tt, w_tt, E_ww + E_wt, SEG_TT };
    R.r[3] = { src_wd, dst_wd, w_wd, E_ww + E_wt + E_tt, SEG_WD };
    R.r[4] = { src_td, dst_td, w_td, E_ww + E_wt + E_tt + E_wd, SEG_TD };

    // ---- bf16 gather table for feat_word ----
    f2b_kernel<<<nb((long long)NW * D / 4), 256, 0, stream>>>(
        feat_word, fw16, NW * D / 4);

    // ---- Topic-side precompute: 4-way parallel MFMA matmuls + combine ----
    MM4 m4;
    m4.W[0] = W_td; m4.W[1] = W_tt; m4.W[2] = W_causal; m4.W[3] = W_noise;
    m4.P[0] = P_td; m4.P[1] = P_tt; m4.P[2] = Pc;       m4.P[3] = Pn;
    mfma_mm4_kernel<<<dim3((NT + 63) / 64, 4), 256, 0, stream>>>(feat_topic, m4, NT);
    combine_topic_kernel<<<nb(NT * D), 256, 0, stream>>>(
        P_td, P_tt, Pc, Pn, effect, bern_td, bern_tt, b_td, b_tt, wtd16, wtt16);

    // ---- CSR build: analytic caps/scan -> partition -> per-bucket CSR ----
    cap_scan_kernel<<<1, 256, 0, stream>>>(
        (float)E_ww / NW, (float)E_wt / NT, (float)E_tt / NT,
        (float)E_wd / NDOC, (float)E_td / NDOC, bucket_base, bucket_cursor, gcur);
    unsigned npb = (unsigned)((E_total + EPB - 1) / EPB);
    partition_kernel<<<npb, 256, 0, stream>>>(R, E_total, bucket_cursor, edataA);
    bucket_csr_kernel<<<NBKT, 1024, 0, stream>>>(
        bucket_base, bucket_cursor, edataA, edataB, offsets, degf, gcur);

    // ---- Phase 1: ww reduce + word projection (fp32 out + bf16 mirror) ----
    reduce_kernel<<<(NW + 3) / 4, 256, 0, stream>>>(
        fw16, offsets, degf, edataB, SEG_WW, NW, S, wsumf);
    mfma_mm_kernel<<<(NW + 63) / 64, 256, 0, stream>>>(
        S + (long long)SEG_WW * D, W_ww, degf + SEG_WW, wsumf + SEG_WW, b_ww,
        nullptr, nullptr, h_word, hw16, NW);

    // ---- Phase 2: merged reduce over wt/tt/wd/td ----
    reduce_p2_kernel<<<(NP2 + 3) / 4, 256, 0, stream>>>(
        hw16, wtt16, wtd16, offsets, degf, edataB, S, wsumf);

    // ---- Final projections (topic + doc merged into one dispatch) ----
    MMF mf;
    mf.X[0] = S + (long long)SEG_WT * D;  mf.X[1] = S + (long long)SEG_WD * D;
    mf.W[0] = W_wt;                        mf.W[1] = W_wd;
    mf.deg[0] = degf + SEG_WT;             mf.deg[1] = degf + SEG_WD;
    mf.wsum[0] = wsumf + SEG_WT;           mf.wsum[1] = wsumf + SEG_WD;
    mf.bias[0] = b_wt;                     mf.bias[1] = b_wd;
    mf.T[0] = S + (long long)SEG_TT * D;   mf.T[1] = S + (long long)SEG_TD * D;
    mf.degT[0] = degf + SEG_TT;            mf.degT[1] = degf + SEG_TD;
    mf.Y[0] = h_topic;                     mf.Y[1] = h_doc;
    mf.n[0] = NT;                          mf.n[1] = NDOC;
    mf.nb0 = (NT + 63) / 64;
    unsigned nbf = (unsigned)((NT + 63) / 64 + (NDOC + 63) / 64);
    mfma_mm2_kernel<<<nbf, 256, 0, stream>>>(mf);

    (void)n_in; (void)in_sizes; (void)out_size; (void)ws_size;
}

// Round 13
// 296.467 us; speedup vs baseline: 1.2968x; 1.0368x over previous
//
#include <hip/hip_runtime.h>

#define D 128
typedef unsigned short u16;
constexpr int NW = 30000;
constexpr int NT = 2000;
constexpr int NDOC = 20000;
constexpr int NSLOT = NW + NT + NT + NDOC + NDOC;   // 74000 destination slots
constexpr int SEG_WW = 0;
constexpr int SEG_WT = NW;                 // 30000
constexpr int SEG_TT = NW + NT;            // 32000
constexpr int SEG_WD = NW + 2 * NT;        // 34000
constexpr int SEG_TD = NW + 2 * NT + NDOC; // 54000
constexpr int NP2 = NT + NT + NDOC + NDOC; // 44000 phase-2 slots

constexpr int BWS = 128;                    // slots per bucket (pow2: slot>>7)
constexpr int NBKT = (NSLOT + BWS - 1) / BWS;  // 579
constexpr int EPB = 2048;                   // edges per partition block (grid ~704)
constexpr int NF2B = (NW * D / 4 + 255) / 256;  // 3750 f2b blocks
constexpr int NBM4 = (NT + 63) / 64;            // 32 blocks per topic matmul

struct RelDesc { const int* src; const int* dst; const float* w; int e0; int seg; };
struct Rels { RelDesc r[5]; };

__device__ __forceinline__ void resolve_rel(const Rels& R, int e,
    const int*& srcp, const int*& dstp, const float*& wp, int& le, int& seg)
{
    int k;
    if (e < R.r[1].e0) k = 0;
    else if (e < R.r[2].e0) k = 1;
    else if (e < R.r[3].e0) k = 2;
    else if (e < R.r[4].e0) k = 3;
    else k = 4;
    srcp = R.r[k].src; dstp = R.r[k].dst; wp = R.r[k].w;
    le = e - R.r[k].e0; seg = R.r[k].seg;
}

__device__ __forceinline__ float b2f(u16 h)
{
    return __uint_as_float(((unsigned)h) << 16);
}
__device__ __forceinline__ u16 f2b(float f)   // round-to-nearest-even
{
    unsigned u = __float_as_uint(f);
    return (u16)((u + 0x7FFF + ((u >> 16) & 1)) >> 16);
}

typedef short bf16x8 __attribute__((ext_vector_type(8)));
typedef float f32x4 __attribute__((ext_vector_type(4)));
constexpr int WPITCH = 136;

// ---------------------------------------------------------------------------
// MFMA tile helpers. Fragment layouts per HW-verified guide mappings:
// A[m=lane&15][k=quad*8+j], B[k][n=lane&15], C/D col=lane&15 row=quad*4+reg.
// ---------------------------------------------------------------------------
__device__ __forceinline__ void stage_wt(
    const float* __restrict__ Wg, u16* Wt, int tid)
{
    for (int i = tid; i < D * D; i += 256) {
        int k = i >> 7, nn = i & 127;          // W[k][nn], coalesced global read
        Wt[nn * WPITCH + k] = f2b(Wg[i]);      // transposed LDS write (one-time)
    }
}

// fp32 source rows (feat_topic)
__device__ __forceinline__ void mfma_tile_f32(
    const float* __restrict__ X, const u16* Wt, int arow, int n,
    int lanelo, int quad, f32x4 acc[8])
{
#pragma unroll
    for (int ct = 0; ct < 8; ++ct) {
        acc[ct][0] = 0.f; acc[ct][1] = 0.f; acc[ct][2] = 0.f; acc[ct][3] = 0.f;
    }
#pragma unroll
    for (int k0 = 0; k0 < 4; ++k0) {
        bf16x8 a;
        if (arow < n) {
            const float* ap = X + (size_t)arow * D + k0 * 32 + quad * 8;
            float4 a0 = *(const float4*)ap;
            float4 a1 = *(const float4*)(ap + 4);
            a[0] = (short)f2b(a0.x); a[1] = (short)f2b(a0.y);
            a[2] = (short)f2b(a0.z); a[3] = (short)f2b(a0.w);
            a[4] = (short)f2b(a1.x); a[5] = (short)f2b(a1.y);
            a[6] = (short)f2b(a1.z); a[7] = (short)f2b(a1.w);
        } else {
#pragma unroll
            for (int j = 0; j < 8; ++j) a[j] = 0;
        }
#pragma unroll
        for (int ct = 0; ct < 8; ++ct) {
            bf16x8 b = *(const bf16x8*)&Wt[(ct * 16 + lanelo) * WPITCH
                                           + k0 * 32 + quad * 8];
            acc[ct] = __builtin_amdgcn_mfma_f32_16x16x32_bf16(a, b, acc[ct], 0, 0, 0);
        }
    }
}

// bf16 source rows (S) — direct fragment load, zero conversion VALU
__device__ __forceinline__ void mfma_tile_b16(
    const u16* __restrict__ Xb, const u16* Wt, int arow, int n,
    int lanelo, int quad, f32x4 acc[8])
{
#pragma unroll
    for (int ct = 0; ct < 8; ++ct) {
        acc[ct][0] = 0.f; acc[ct][1] = 0.f; acc[ct][2] = 0.f; acc[ct][3] = 0.f;
    }
#pragma unroll
    for (int k0 = 0; k0 < 4; ++k0) {
        bf16x8 a;
        if (arow < n) {
            a = *(const bf16x8*)(Xb + (size_t)arow * D + k0 * 32 + quad * 8);
        } else {
#pragma unroll
            for (int j = 0; j < 8; ++j) a[j] = 0;
        }
#pragma unroll
        for (int ct = 0; ct < 8; ++ct) {
            bf16x8 b = *(const bf16x8*)&Wt[(ct * 16 + lanelo) * WPITCH
                                           + k0 * 32 + quad * 8];
            acc[ct] = __builtin_amdgcn_mfma_f32_16x16x32_bf16(a, b, acc[ct], 0, 0, 0);
        }
    }
}

// ---------------------------------------------------------------------------
// prep kernel: block 0 = analytic cap scan; blocks [1,1+NF2B) = feat_word
// fp32->bf16; blocks [1+NF2B,..) = 4 topic matmuls (32 blocks each). All
// three sub-tasks are mutually independent (merged to cut launch gaps).
// ---------------------------------------------------------------------------
struct MM4 { const float* W[4]; float* P[4]; };

__global__ __launch_bounds__(256) void prep_kernel(
    const float* __restrict__ feat_word, u16* __restrict__ fw16,
    const float* __restrict__ feat_topic, MM4 m4,
    float m_ww, float m_wt, float m_tt, float m_wd, float m_td,
    int* __restrict__ bucket_base, int* __restrict__ bucket_cursor,
    int* __restrict__ gcur)
{
    __shared__ u16 Wt[D * WPITCH];
    __shared__ int chs[256];
    __shared__ int vals[256 * 3];
    int tid = threadIdx.x;

    if (blockIdx.x == 0) {
        // ---- cap scan: analytic bucket capacities + prefix sum ----
        if (tid == 0) *gcur = 0;
        int s = 0;
        for (int j = 0; j < 3; ++j) {
            int k = tid * 3 + j;
            int c = 0;
            if (k < NBKT) {
                int a = k * BWS, b = min(a + BWS, NSLOT);
                auto ov = [&](int lo, int hi) {
                    return (float)max(0, min(b, hi) - max(a, lo));
                };
                float ex = ov(SEG_WW, SEG_WT) * m_ww + ov(SEG_WT, SEG_TT) * m_wt
                         + ov(SEG_TT, SEG_WD) * m_tt + ov(SEG_WD, SEG_TD) * m_wd
                         + ov(SEG_TD, NSLOT) * m_td;
                c = (int)(ex * 1.5f) + 128;
            }
            vals[tid * 3 + j] = c;
            s += c;
        }
        chs[tid] = s;
        __syncthreads();
        for (int off = 1; off < 256; off <<= 1) {
            int t = (tid >= off) ? chs[tid - off] : 0;
            __syncthreads();
            chs[tid] += t;
            __syncthreads();
        }
        int run = (tid == 0) ? 0 : chs[tid - 1];
        for (int j = 0; j < 3; ++j) {
            int k = tid * 3 + j;
            if (k < NBKT) {
                bucket_base[k] = run;
                bucket_cursor[k] = run;
                run += vals[tid * 3 + j];
            }
        }
    } else if (blockIdx.x <= NF2B) {
        // ---- f2b: feat_word -> bf16 table ----
        int i = (blockIdx.x - 1) * 256 + tid;
        if (i < NW * D / 4) {
            float4 v = ((const float4*)feat_word)[i];
            ushort4 o;
            o.x = f2b(v.x); o.y = f2b(v.y); o.z = f2b(v.z); o.w = f2b(v.w);
            ((ushort4*)fw16)[i] = o;
        }
    } else {
        // ---- mm4: 4 parallel topic matmuls ----
        int idx = blockIdx.x - 1 - NF2B;
        int which = idx / NBM4;
        int bx = idx % NBM4;
        stage_wt(m4.W[which], Wt, tid);
        __syncthreads();
        int wv = tid >> 6, lane = tid & 63;
        int lanelo = lane & 15, quad = lane >> 4;
        int rowbase = bx * 64 + wv * 16;
        f32x4 acc[8];
        mfma_tile_f32(feat_topic, Wt, rowbase + lanelo, NT, lanelo, quad, acc);
        float* Y = m4.P[which];
        int rbase = rowbase + quad * 4;
#pragma unroll
        for (int r = 0; r < 4; ++r) {
            int row = rbase + r;
            if (row >= NT) continue;
#pragma unroll
            for (int ct = 0; ct < 8; ++ct)
                Y[(size_t)row * D + ct * 16 + lanelo] = acc[ct][r];
        }
    }
}

// ---------------------------------------------------------------------------
// partition + combine merged (mutually independent):
// blocks [0,npb): partition edges into capacity-padded edataA regions.
// blocks [npb,..): Wh combine -> bf16 wtd16/wtt16.
// ---------------------------------------------------------------------------
__global__ __launch_bounds__(256) void part_combine_kernel(
    Rels R, int Etot, int* __restrict__ bucket_cursor, int2* __restrict__ edataA,
    const float* __restrict__ P_td, const float* __restrict__ P_tt,
    const float* __restrict__ Pc, const float* __restrict__ Pn,
    const float* __restrict__ effect, const float* __restrict__ bern_td,
    const float* __restrict__ bern_tt,
    const float* __restrict__ b_td, const float* __restrict__ b_tt,
    u16* __restrict__ wtd16, u16* __restrict__ wtt16, int npb)
{
    __shared__ int hist[NBKT];
    __shared__ int baseL[NBKT];
    __shared__ u16 bkt[EPB];
    __shared__ unsigned char dl[EPB];
    int tid = threadIdx.x;

    if ((int)blockIdx.x >= npb) {
        int i = ((int)blockIdx.x - npb) * 256 + tid;
        if (i < NT * D) {
            int row = i >> 7;
            int col = i & (D - 1);
            float eff = effect[row];
            float causal = (eff != 0.f) ? 1.f : 0.f;
            float zero = (eff == 0.f) ? 1.f : 0.f;
            float rmtd = bern_td[row] * zero;
            float rmtt = bern_tt[row] * zero;
            float pc = Pc[i];
            float pn = Pn[i];
            wtd16[i] = f2b(P_td[i] + b_td[col] + causal * pc - rmtd * pn);
            wtt16[i] = f2b(P_tt[i] + b_tt[col] + causal * pc - rmtt * pn);
        }
        return;
    }

    for (int i = tid; i < NBKT; i += 256) hist[i] = 0;
    __syncthreads();
    int base_e = blockIdx.x * EPB;
    for (int r = 0; r < EPB / 256; ++r) {
        int idx = r * 256 + tid;
        int e = base_e + idx;
        if (e < Etot) {
            const int *srcp, *dstp; const float* wp; int le, seg;
            resolve_rel(R, e, srcp, dstp, wp, le, seg);
            int g = seg + dstp[le];
            bkt[idx] = (u16)(g >> 7);
            dl[idx] = (unsigned char)(g & 127);
            atomicAdd(&hist[g >> 7], 1);
        } else {
            bkt[idx] = 0xFFFF;
        }
    }
    __syncthreads();
    for (int i = tid; i < NBKT; i += 256)
        baseL[i] = hist[i] ? atomicAdd(&bucket_cursor[i], hist[i]) : 0;
    __syncthreads();
    for (int i = tid; i < NBKT; i += 256) hist[i] = 0;
    __syncthreads();
    for (int r = 0; r < EPB / 256; ++r) {
        int idx = r * 256 + tid;
        int e = base_e + idx;
        if (e < Etot) {
            const int *srcp, *dstp; const float* wp; int le, seg;
            resolve_rel(R, e, srcp, dstp, wp, le, seg);
            int b = bkt[idx];
            int rk = atomicAdd(&hist[b], 1);
            edataA[baseL[b] + rk] =
                make_int2(srcp[le] | ((int)dl[idx] << 15), __float_as_int(wp[le]));
        }
    }
}

// ---------------------------------------------------------------------------
// B: one block (1024 threads) per bucket. LDS histogram over 128 slots ->
// scan -> COMPACT into edataB via one global atomic (gcur). Emits offsets +
// degf + edges in CSR order.
// ---------------------------------------------------------------------------
__global__ __launch_bounds__(1024) void bucket_csr_kernel(
    const int* __restrict__ bucket_base, const int* __restrict__ bucket_cursor,
    const int2* __restrict__ edataA, int2* __restrict__ edataB,
    int* __restrict__ offsets, float* __restrict__ degf, int* __restrict__ gcur)
{
    int k = blockIdx.x;
    int bstart = bucket_base[k], bend = bucket_cursor[k];
    int nk = bend - bstart;
    __shared__ int h2[BWS];
    __shared__ int exc[BWS];
    __shared__ int cbase;
    int tid = threadIdx.x;
    if (tid == 0) cbase = atomicAdd(gcur, nk);   // compacted output base
    if (tid < BWS) h2[tid] = 0;
    __syncthreads();
    for (int i = bstart + tid; i < bend; i += 1024) {
        int dloc = (edataA[i].x >> 15) & 127;
        atomicAdd(&h2[dloc], 1);
    }
    __syncthreads();
    if (tid < BWS) exc[tid] = h2[tid];
    __syncthreads();
    for (int off = 1; off < BWS; off <<= 1) {
        int t = 0;
        if (tid < BWS && tid >= off) t = exc[tid - off];
        __syncthreads();
        if (tid < BWS) exc[tid] += t;
        __syncthreads();
    }
    if (tid < BWS) exc[tid] -= h2[tid];   // exclusive
    __syncthreads();
    int slot0 = k * BWS;
    if (tid < BWS && slot0 + tid < NSLOT) {
        offsets[slot0 + tid] = cbase + exc[tid];
        degf[slot0 + tid] = (float)h2[tid];
    }
    __syncthreads();
    if (tid < BWS) h2[tid] = 0;
    __syncthreads();
    for (int i = bstart + tid; i < bend; i += 1024) {
        int2 e = edataA[i];
        int dloc = (e.x >> 15) & 127;
        int rk = atomicAdd(&h2[dloc], 1);
        edataB[cbase + exc[dloc] + rk] = e;
    }
}

// ---------------------------------------------------------------------------
// Segmented reduction (one wave per dst slot). Gather bf16, accumulate fp32,
// 16-edge main loop (8 gathers in flight per 32-lane half). S stored bf16.
// ---------------------------------------------------------------------------
__device__ __forceinline__ void reduce_one(
    const u16* __restrict__ Xb, const int* __restrict__ offsets,
    const float* __restrict__ degf, const int2* __restrict__ edata, int slot,
    int lane, u16* __restrict__ Sb, float* __restrict__ wsumf)
{
    int start = offsets[slot];
    int end = start + (int)degf[slot];
    int half = lane >> 5;
    int q = (lane & 31) * 4;   // element offset within row (4 per lane)
    float4 acc = make_float4(0.f, 0.f, 0.f, 0.f);
    float wacc = 0.f;
    int j = start;
    for (; j + 16 <= end; j += 16) {       // 8 gathers in flight per lane
        int2 ee[8];
        ushort4 vv[8];
#pragma unroll
        for (int t = 0; t < 8; ++t) ee[t] = edata[j + 2 * t + half];
#pragma unroll
        for (int t = 0; t < 8; ++t)
            vv[t] = *(const ushort4*)(Xb + (size_t)(ee[t].x & 0x7FFF) * D + q);
#pragma unroll
        for (int t = 0; t < 8; ++t) {
            float w = __int_as_float(ee[t].y);
            acc.x = fmaf(w, b2f(vv[t].x), acc.x);
            acc.y = fmaf(w, b2f(vv[t].y), acc.y);
            acc.z = fmaf(w, b2f(vv[t].z), acc.z);
            acc.w = fmaf(w, b2f(vv[t].w), acc.w);
            wacc += w;
        }
    }
    if (j + 8 <= end) {
        int2 ee[4];
        ushort4 vv[4];
#pragma unroll
        for (int t = 0; t < 4; ++t) ee[t] = edata[j + 2 * t + half];
#pragma unroll
        for (int t = 0; t < 4; ++t)
            vv[t] = *(const ushort4*)(Xb + (size_t)(ee[t].x & 0x7FFF) * D + q);
#pragma unroll
        for (int t = 0; t < 4; ++t) {
            float w = __int_as_float(ee[t].y);
            acc.x = fmaf(w, b2f(vv[t].x), acc.x);
            acc.y = fmaf(w, b2f(vv[t].y), acc.y);
            acc.z = fmaf(w, b2f(vv[t].z), acc.z);
            acc.w = fmaf(w, b2f(vv[t].w), acc.w);
            wacc += w;
        }
        j += 8;
    }
    if (j + 4 <= end) {
        int2 ea = edata[j + half];
        int2 eb = edata[j + 2 + half];
        ushort4 va = *(const ushort4*)(Xb + (size_t)(ea.x & 0x7FFF) * D + q);
        ushort4 vb = *(const ushort4*)(Xb + (size_t)(eb.x & 0x7FFF) * D + q);
        float wa = __int_as_float(ea.y);
        float wb = __int_as_float(eb.y);
        acc.x = fmaf(wa, b2f(va.x), acc.x); acc.y = fmaf(wa, b2f(va.y), acc.y);
        acc.z = fmaf(wa, b2f(va.z), acc.z); acc.w = fmaf(wa, b2f(va.w), acc.w);
        acc.x = fmaf(wb, b2f(vb.x), acc.x); acc.y = fmaf(wb, b2f(vb.y), acc.y);
        acc.z = fmaf(wb, b2f(vb.z), acc.z); acc.w = fmaf(wb, b2f(vb.w), acc.w);
        wacc += wa + wb;
        j += 4;
    }
    for (; j < end; j += 2) {
        int jj = j + half;
        int2 e = edata[jj < end ? jj : (end - 1)];
        float w = (jj < end) ? __int_as_float(e.y) : 0.f;
        ushort4 v = *(const ushort4*)(Xb + (size_t)(e.x & 0x7FFF) * D + q);
        acc.x = fmaf(w, b2f(v.x), acc.x); acc.y = fmaf(w, b2f(v.y), acc.y);
        acc.z = fmaf(w, b2f(v.z), acc.z); acc.w = fmaf(w, b2f(v.w), acc.w);
        wacc += w;
    }
    acc.x += __shfl_xor(acc.x, 32);
    acc.y += __shfl_xor(acc.y, 32);
    acc.z += __shfl_xor(acc.z, 32);
    acc.w += __shfl_xor(acc.w, 32);
    wacc  += __shfl_xor(wacc, 32);
    if (half == 0) {
        ushort4 o;
        o.x = f2b(acc.x); o.y = f2b(acc.y); o.z = f2b(acc.z); o.w = f2b(acc.w);
        *(ushort4*)(Sb + (size_t)slot * D + q) = o;
    }
    if (lane == 0 && wsumf) wsumf[slot] = wacc;
}

__global__ __launch_bounds__(256) void reduce_kernel(
    const u16* __restrict__ Xb, const int* __restrict__ offsets,
    const float* __restrict__ degf, const int2* __restrict__ edata,
    int slot0, int nslots, u16* __restrict__ Sb, float* __restrict__ wsumf)
{
    int rel = blockIdx.x * 4 + (threadIdx.x >> 6);
    if (rel >= nslots) return;
    reduce_one(Xb, offsets, degf, edata, slot0 + rel, threadIdx.x & 63, Sb, wsumf);
}

__global__ __launch_bounds__(256) void reduce_p2_kernel(
    const u16* __restrict__ hw16, const u16* __restrict__ wtt16,
    const u16* __restrict__ wtd16, const int* __restrict__ offsets,
    const float* __restrict__ degf, const int2* __restrict__ edata,
    u16* __restrict__ Sb, float* __restrict__ wsumf)
{
    int rel = blockIdx.x * 4 + (threadIdx.x >> 6);
    if (rel >= NP2) return;
    const u16* X;
    if (rel < NT)                 X = hw16;   // wt
    else if (rel < 2 * NT)        X = wtt16;  // tt
    else if (rel < 2 * NT + NDOC) X = hw16;   // wd
    else                          X = wtd16;  // td
    reduce_one(X, offsets, degf, edata, SEG_WT + rel, threadIdx.x & 63, Sb, wsumf);
}

// ---------------------------------------------------------------------------
// MFMA mm over bf16 S rows: Y = (S@W + wsum*bias)/deg [+ T/degT], optional
// bf16 mirror Yb. Block = 4 waves x 16 rows.
// ---------------------------------------------------------------------------
__device__ __forceinline__ void mfma_mm_body(
    const u16* __restrict__ Xb, const float* __restrict__ Wg,
    const float* __restrict__ deg, const float* __restrict__ wsum,
    const float* __restrict__ bias,
    const u16* __restrict__ T, const float* __restrict__ degT,
    float* __restrict__ Y, u16* __restrict__ Yb, int n,
    u16* Wt, int tid, int bx)
{
    stage_wt(Wg, Wt, tid);
    __syncthreads();
    int wv = tid >> 6, lane = tid & 63;
    int lanelo = lane & 15, quad = lane >> 4;
    int rowbase = bx * 64 + wv * 16;
    f32x4 acc[8];
    mfma_tile_b16(Xb, Wt, rowbase + lanelo, n, lanelo, quad, acc);

    int rbase = rowbase + quad * 4;
#pragma unroll
    for (int r = 0; r < 4; ++r) {
        int row = rbase + r;
        if (row >= n) continue;
        float dgv = deg[row];
        float wsv = wsum ? wsum[row] : 0.f;
        float dtv = degT ? degT[row] : 0.f;
#pragma unroll
        for (int ct = 0; ct < 8; ++ct) {
            int col = ct * 16 + lanelo;
            float y = acc[ct][r];
            y = dgv > 0.f ? (y + wsv * bias[col]) / dgv : 0.f;
            if (T && dtv > 0.f) y += b2f(T[(size_t)row * D + col]) / dtv;
            Y[(size_t)row * D + col] = y;
            if (Yb) Yb[(size_t)row * D + col] = f2b(y);
        }
    }
}

__global__ __launch_bounds__(256) void mfma_mm_kernel(
    const u16* __restrict__ Xb, const float* __restrict__ Wg,
    const float* __restrict__ deg, const float* __restrict__ wsum,
    const float* __restrict__ bias,
    const u16* __restrict__ T, const float* __restrict__ degT,
    float* __restrict__ Y, u16* __restrict__ Yb, int n)
{
    __shared__ u16 Wt[D * WPITCH];
    mfma_mm_body(Xb, Wg, deg, wsum, bias, T, degT, Y, Yb, n,
                 Wt, threadIdx.x, blockIdx.x);
}

// Final projections merged: blocks [0,nb0) -> topic, [nb0,..) -> doc.
struct MMF {
    const u16* X[2]; const float* W[2]; const float* deg[2];
    const float* wsum[2]; const float* bias[2];
    const u16* T[2]; const float* degT[2];
    float* Y[2]; int n[2]; int nb0;
};
__global__ __launch_bounds__(256) void mfma_mm2_kernel(MMF p)
{
    __shared__ u16 Wt[D * WPITCH];
    int which = (int)(blockIdx.x >= (unsigned)p.nb0);
    int bx = which ? (int)blockIdx.x - p.nb0 : (int)blockIdx.x;
    mfma_mm_body(p.X[which], p.W[which], p.deg[which], p.wsum[which],
                 p.bias[which], p.T[which], p.degT[which], p.Y[which],
                 nullptr, p.n[which], Wt, threadIdx.x, bx);
}

extern "C" void kernel_launch(void* const* d_in, const int* in_sizes, int n_in,
                              void* d_out, int out_size, void* d_ws, size_t ws_size,
                              hipStream_t stream)
{
    const float* feat_word  = (const float*)d_in[0];
    const float* feat_topic = (const float*)d_in[1];
    const float* effect     = (const float*)d_in[2];
    const float* bern_td    = (const float*)d_in[3];
    const float* bern_tt    = (const float*)d_in[4];
    const int*   src_ww = (const int*)d_in[5];
    const int*   dst_ww = (const int*)d_in[6];
    const float* w_ww   = (const float*)d_in[7];
    const int*   src_wt = (const int*)d_in[8];
    const int*   dst_wt = (const int*)d_in[9];
    const float* w_wt   = (const float*)d_in[10];
    const int*   src_wd = (const int*)d_in[11];
    const int*   dst_wd = (const int*)d_in[12];
    const float* w_wd   = (const float*)d_in[13];
    const int*   src_td = (const int*)d_in[14];
    const int*   dst_td = (const int*)d_in[15];
    const float* w_td   = (const float*)d_in[16];
    const int*   src_tt = (const int*)d_in[17];
    const int*   dst_tt = (const int*)d_in[18];
    const float* w_tt   = (const float*)d_in[19];
    const float* W_ww = (const float*)d_in[20];
    const float* b_ww = (const float*)d_in[21];
    const float* W_wt = (const float*)d_in[22];
    const float* b_wt = (const float*)d_in[23];
    const float* W_wd = (const float*)d_in[24];
    const float* b_wd = (const float*)d_in[25];
    const float* W_td = (const float*)d_in[26];
    const float* b_td = (const float*)d_in[27];
    const float* W_tt = (const float*)d_in[28];
    const float* b_tt = (const float*)d_in[29];
    const float* W_causal = (const float*)d_in[30];
    const float* W_noise  = (const float*)d_in[31];

    const int E_ww = in_sizes[5];
    const int E_wt = in_sizes[8];
    const int E_wd = in_sizes[11];
    const int E_td = in_sizes[14];
    const int E_tt = in_sizes[17];
    const int E_total = E_ww + E_wt + E_wd + E_td + E_tt;
    // padded edataA capacity: sum of per-bucket caps <= 1.5*E_total + 128*NBKT
    const long long capA = (long long)(1.5 * E_total) + 128LL * NBKT + 256;

    // ---- workspace layout (4-byte units; dedicated regions, NO overlays) ----
    float* ws = (float*)d_ws;
    u16*   Sb    = (u16*)ws; ws += (long long)NSLOT * D / 2;   // bf16 agg sums
    float* degf  = ws; ws += NSLOT;
    float* wsumf = ws; ws += NSLOT;
    int*   offsets      = (int*)ws; ws += NSLOT + 1;
    int*   bucket_base  = (int*)ws; ws += NBKT + 1;
    int*   bucket_cursor= (int*)ws; ws += NBKT;
    int*   gcur         = (int*)ws; ws += 1;
    ws += ((size_t)(ws - (float*)d_ws) & 1);          // 8B align
    int2*  edataB   = (int2*)ws; ws += (long long)2 * E_total;   // compact coords
    int2*  edataA   = (int2*)ws; ws += 2 * capA;                 // padded coords
    float* P_td  = ws; ws += (long long)NT * D;
    float* P_tt  = ws; ws += (long long)NT * D;
    float* Pc    = ws; ws += (long long)NT * D;
    float* Pn    = ws; ws += (long long)NT * D;
    u16*   fw16     = (u16*)ws;  ws += (long long)NW * D / 2;   // bf16 feat_word
    u16*   hw16     = (u16*)ws;  ws += (long long)NW * D / 2;   // bf16 h_word
    u16*   wtd16    = (u16*)ws;  ws += (long long)NT * D / 2;
    u16*   wtt16    = (u16*)ws;  ws += (long long)NT * D / 2;

    float* h_word  = (float*)d_out;
    float* h_topic = h_word + (long long)NW * D;
    float* h_doc   = h_topic + (long long)NT * D;

    auto nb = [](long long n) { return (unsigned)((n + 255) / 256); };

    Rels R;
    R.r[0] = { src_ww, dst_ww, w_ww, 0, SEG_WW };
    R.r[1] = { src_wt, dst_wt, w_wt, E_ww, SEG_WT };
    R.r[2] = { src_tt, dst_tt, w_tt, E_ww + E_wt, SEG_TT };
    R.r[3] = { src_wd, dst_wd, w_wd, E_ww + E_wt + E_tt, SEG_WD };
    R.r[4] = { src_td, dst_td, w_td, E_ww + E_wt + E_tt + E_wd, SEG_TD };

    // ---- merged prep: cap_scan + f2b + 4 topic matmuls ----
    MM4 m4;
    m4.W[0] = W_td; m4.W[1] = W_tt; m4.W[2] = W_causal; m4.W[3] = W_noise;
    m4.P[0] = P_td; m4.P[1] = P_tt; m4.P[2] = Pc;       m4.P[3] = Pn;
    prep_kernel<<<1 + NF2B + 4 * NBM4, 256, 0, stream>>>(
        feat_word, fw16, feat_topic, m4,
        (float)E_ww / NW, (float)E_wt / NT, (float)E_tt / NT,
        (float)E_wd / NDOC, (float)E_td / NDOC,
        bucket_base, bucket_cursor, gcur);

    // ---- merged partition + Wh combine ----
    unsigned npb = (unsigned)((E_total + EPB - 1) / EPB);
    part_combine_kernel<<<npb + nb((long long)NT * D), 256, 0, stream>>>(
        R, E_total, bucket_cursor, edataA,
        P_td, P_tt, Pc, Pn, effect, bern_td, bern_tt, b_td, b_tt,
        wtd16, wtt16, (int)npb);

    bucket_csr_kernel<<<NBKT, 1024, 0, stream>>>(
        bucket_base, bucket_cursor, edataA, edataB, offsets, degf, gcur);

    // ---- Phase 1: ww reduce + word projection (fp32 out + bf16 mirror) ----
    reduce_kernel<<<(NW + 3) / 4, 256, 0, stream>>>(
        fw16, offsets, degf, edataB, SEG_WW, NW, Sb, wsumf);
    mfma_mm_kernel<<<(NW + 63) / 64, 256, 0, stream>>>(
        Sb + (long long)SEG_WW * D, W_ww, degf + SEG_WW, wsumf + SEG_WW, b_ww,
        nullptr, nullptr, h_word, hw16, NW);

    // ---- Phase 2: merged reduce over wt/tt/wd/td ----
    reduce_p2_kernel<<<(NP2 + 3) / 4, 256, 0, stream>>>(
        hw16, wtt16, wtd16, offsets, degf, edataB, Sb, wsumf);

    // ---- Final projections (topic + doc merged into one dispatch) ----
    MMF mf;
    mf.X[0] = Sb + (long long)SEG_WT * D;  mf.X[1] = Sb + (long long)SEG_WD * D;
    mf.W[0] = W_wt;                        mf.W[1] = W_wd;
    mf.deg[0] = degf + SEG_WT;             mf.deg[1] = degf + SEG_WD;
    mf.wsum[0] = wsumf + SEG_WT;           mf.wsum[1] = wsumf + SEG_WD;
    mf.bias[0] = b_wt;                     mf.bias[1] = b_wd;
    mf.T[0] = Sb + (long long)SEG_TT * D;  mf.T[1] = Sb + (long long)SEG_TD * D;
    mf.degT[0] = degf + SEG_TT;            mf.degT[1] = degf + SEG_TD;
    mf.Y[0] = h_topic;                     mf.Y[1] = h_doc;
    mf.n[0] = NT;                          mf.n[1] = NDOC;
    mf.nb0 = (NT + 63) / 64;
    unsigned nbf = (unsigned)((NT + 63) / 64 + (NDOC + 63) / 64);
    mfma_mm2_kernel<<<nbf, 256, 0, stream>>>(mf);

    (void)n_in; (void)in_sizes; (void)out_size; (void)ws_size;
}

// Round 14
// 291.446 us; speedup vs baseline: 1.3192x; 1.0172x over previous
//
#include <hip/hip_runtime.h>

#define D 128
typedef unsigned short u16;
constexpr int NW = 30000;
constexpr int NT = 2000;
constexpr int NDOC = 20000;
constexpr int NSLOT = NW + NT + NT + NDOC + NDOC;   // 74000 destination slots
constexpr int SEG_WW = 0;
constexpr int SEG_WT = NW;                 // 30000
constexpr int SEG_TT = NW + NT;            // 32000
constexpr int SEG_WD = NW + 2 * NT;        // 34000
constexpr int SEG_TD = NW + 2 * NT + NDOC; // 54000
constexpr int NP2 = NT + NT + NDOC + NDOC; // 44000 phase-2 slots

constexpr int BWS = 128;                    // slots per bucket (pow2: slot>>7)
constexpr int NBKT = (NSLOT + BWS - 1) / BWS;  // 579
constexpr int EPB = 4096;                   // edges per partition block (grid ~352)
constexpr int NF2B = (NW * D / 4 + 255) / 256;  // 3750 f2b blocks
constexpr int NBM4 = (NT + 63) / 64;            // 32 blocks per topic matmul

struct RelDesc { const int* src; const int* dst; const float* w; int e0; int seg; };
struct Rels { RelDesc r[5]; };

__device__ __forceinline__ void resolve_rel(const Rels& R, int e,
    const int*& srcp, const int*& dstp, const float*& wp, int& le, int& seg)
{
    int k;
    if (e < R.r[1].e0) k = 0;
    else if (e < R.r[2].e0) k = 1;
    else if (e < R.r[3].e0) k = 2;
    else if (e < R.r[4].e0) k = 3;
    else k = 4;
    srcp = R.r[k].src; dstp = R.r[k].dst; wp = R.r[k].w;
    le = e - R.r[k].e0; seg = R.r[k].seg;
}

__device__ __forceinline__ float b2f(u16 h)
{
    return __uint_as_float(((unsigned)h) << 16);
}
__device__ __forceinline__ u16 f2b(float f)   // round-to-nearest-even
{
    unsigned u = __float_as_uint(f);
    return (u16)((u + 0x7FFF + ((u >> 16) & 1)) >> 16);
}

typedef short bf16x8 __attribute__((ext_vector_type(8)));
typedef float f32x4 __attribute__((ext_vector_type(4)));
constexpr int WPITCH = 136;

// ---------------------------------------------------------------------------
// MFMA tile helpers. Fragment layouts per HW-verified guide mappings:
// A[m=lane&15][k=quad*8+j], B[k][n=lane&15], C/D col=lane&15 row=quad*4+reg.
// ---------------------------------------------------------------------------
__device__ __forceinline__ void stage_wt(
    const float* __restrict__ Wg, u16* Wt, int tid)
{
    for (int i = tid; i < D * D; i += 256) {
        int k = i >> 7, nn = i & 127;          // W[k][nn], coalesced global read
        Wt[nn * WPITCH + k] = f2b(Wg[i]);      // transposed LDS write (one-time)
    }
}

// fp32 source rows (feat_topic)
__device__ __forceinline__ void mfma_tile_f32(
    const float* __restrict__ X, const u16* Wt, int arow, int n,
    int lanelo, int quad, f32x4 acc[8])
{
#pragma unroll
    for (int ct = 0; ct < 8; ++ct) {
        acc[ct][0] = 0.f; acc[ct][1] = 0.f; acc[ct][2] = 0.f; acc[ct][3] = 0.f;
    }
#pragma unroll
    for (int k0 = 0; k0 < 4; ++k0) {
        bf16x8 a;
        if (arow < n) {
            const float* ap = X + (size_t)arow * D + k0 * 32 + quad * 8;
            float4 a0 = *(const float4*)ap;
            float4 a1 = *(const float4*)(ap + 4);
            a[0] = (short)f2b(a0.x); a[1] = (short)f2b(a0.y);
            a[2] = (short)f2b(a0.z); a[3] = (short)f2b(a0.w);
            a[4] = (short)f2b(a1.x); a[5] = (short)f2b(a1.y);
            a[6] = (short)f2b(a1.z); a[7] = (short)f2b(a1.w);
        } else {
#pragma unroll
            for (int j = 0; j < 8; ++j) a[j] = 0;
        }
#pragma unroll
        for (int ct = 0; ct < 8; ++ct) {
            bf16x8 b = *(const bf16x8*)&Wt[(ct * 16 + lanelo) * WPITCH
                                           + k0 * 32 + quad * 8];
            acc[ct] = __builtin_amdgcn_mfma_f32_16x16x32_bf16(a, b, acc[ct], 0, 0, 0);
        }
    }
}

// bf16 source rows (S) — direct fragment load, zero conversion VALU
__device__ __forceinline__ void mfma_tile_b16(
    const u16* __restrict__ Xb, const u16* Wt, int arow, int n,
    int lanelo, int quad, f32x4 acc[8])
{
#pragma unroll
    for (int ct = 0; ct < 8; ++ct) {
        acc[ct][0] = 0.f; acc[ct][1] = 0.f; acc[ct][2] = 0.f; acc[ct][3] = 0.f;
    }
#pragma unroll
    for (int k0 = 0; k0 < 4; ++k0) {
        bf16x8 a;
        if (arow < n) {
            a = *(const bf16x8*)(Xb + (size_t)arow * D + k0 * 32 + quad * 8);
        } else {
#pragma unroll
            for (int j = 0; j < 8; ++j) a[j] = 0;
        }
#pragma unroll
        for (int ct = 0; ct < 8; ++ct) {
            bf16x8 b = *(const bf16x8*)&Wt[(ct * 16 + lanelo) * WPITCH
                                           + k0 * 32 + quad * 8];
            acc[ct] = __builtin_amdgcn_mfma_f32_16x16x32_bf16(a, b, acc[ct], 0, 0, 0);
        }
    }
}

// ---------------------------------------------------------------------------
// prep kernel: block 0 = analytic cap scan; blocks [1,1+NF2B) = feat_word
// fp32->bf16; blocks [1+NF2B,..) = 4 topic matmuls (32 blocks each). All
// three sub-tasks are mutually independent (merged to cut launch gaps).
// ---------------------------------------------------------------------------
struct MM4 { const float* W[4]; float* P[4]; };

__global__ __launch_bounds__(256) void prep_kernel(
    const float* __restrict__ feat_word, u16* __restrict__ fw16,
    const float* __restrict__ feat_topic, MM4 m4,
    float m_ww, float m_wt, float m_tt, float m_wd, float m_td,
    int* __restrict__ bucket_base, int* __restrict__ bucket_cursor,
    int* __restrict__ gcur)
{
    __shared__ u16 Wt[D * WPITCH];
    __shared__ int chs[256];
    __shared__ int vals[256 * 3];
    int tid = threadIdx.x;

    if (blockIdx.x == 0) {
        // ---- cap scan: analytic bucket capacities + prefix sum ----
        if (tid == 0) *gcur = 0;
        int s = 0;
        for (int j = 0; j < 3; ++j) {
            int k = tid * 3 + j;
            int c = 0;
            if (k < NBKT) {
                int a = k * BWS, b = min(a + BWS, NSLOT);
                auto ov = [&](int lo, int hi) {
                    return (float)max(0, min(b, hi) - max(a, lo));
                };
                float ex = ov(SEG_WW, SEG_WT) * m_ww + ov(SEG_WT, SEG_TT) * m_wt
                         + ov(SEG_TT, SEG_WD) * m_tt + ov(SEG_WD, SEG_TD) * m_wd
                         + ov(SEG_TD, NSLOT) * m_td;
                c = (int)(ex * 1.5f) + 128;
            }
            vals[tid * 3 + j] = c;
            s += c;
        }
        chs[tid] = s;
        __syncthreads();
        for (int off = 1; off < 256; off <<= 1) {
            int t = (tid >= off) ? chs[tid - off] : 0;
            __syncthreads();
            chs[tid] += t;
            __syncthreads();
        }
        int run = (tid == 0) ? 0 : chs[tid - 1];
        for (int j = 0; j < 3; ++j) {
            int k = tid * 3 + j;
            if (k < NBKT) {
                bucket_base[k] = run;
                bucket_cursor[k] = run;
                run += vals[tid * 3 + j];
            }
        }
    } else if (blockIdx.x <= NF2B) {
        // ---- f2b: feat_word -> bf16 table ----
        int i = (blockIdx.x - 1) * 256 + tid;
        if (i < NW * D / 4) {
            float4 v = ((const float4*)feat_word)[i];
            ushort4 o;
            o.x = f2b(v.x); o.y = f2b(v.y); o.z = f2b(v.z); o.w = f2b(v.w);
            ((ushort4*)fw16)[i] = o;
        }
    } else {
        // ---- mm4: 4 parallel topic matmuls ----
        int idx = blockIdx.x - 1 - NF2B;
        int which = idx / NBM4;
        int bx = idx % NBM4;
        stage_wt(m4.W[which], Wt, tid);
        __syncthreads();
        int wv = tid >> 6, lane = tid & 63;
        int lanelo = lane & 15, quad = lane >> 4;
        int rowbase = bx * 64 + wv * 16;
        f32x4 acc[8];
        mfma_tile_f32(feat_topic, Wt, rowbase + lanelo, NT, lanelo, quad, acc);
        float* Y = m4.P[which];
        int rbase = rowbase + quad * 4;
#pragma unroll
        for (int r = 0; r < 4; ++r) {
            int row = rbase + r;
            if (row >= NT) continue;
#pragma unroll
            for (int ct = 0; ct < 8; ++ct)
                Y[(size_t)row * D + ct * 16 + lanelo] = acc[ct][r];
        }
    }
}

// ---------------------------------------------------------------------------
// partition + combine merged (mutually independent):
// blocks [0,npb): partition edges into capacity-padded edataA regions.
//   Single-read version: pass 1 resolves each edge ONCE, staging the packed
//   int2 entry (src|dloc<<15, w) in LDS; pass 2 writes from LDS (the old
//   version re-read src/w from global: +11.5MB + duplicated resolve VALU).
//   EPB=4096 halves per-bucket claim atomics and doubles chunk contiguity.
// blocks [npb,..): Wh combine -> bf16 wtd16/wtt16.
// ---------------------------------------------------------------------------
__global__ __launch_bounds__(256) void part_combine_kernel(
    Rels R, int Etot, int* __restrict__ bucket_cursor, int2* __restrict__ edataA,
    const float* __restrict__ P_td, const float* __restrict__ P_tt,
    const float* __restrict__ Pc, const float* __restrict__ Pn,
    const float* __restrict__ effect, const float* __restrict__ bern_td,
    const float* __restrict__ bern_tt,
    const float* __restrict__ b_td, const float* __restrict__ b_tt,
    u16* __restrict__ wtd16, u16* __restrict__ wtt16, int npb)
{
    __shared__ int hist[NBKT];
    __shared__ int baseL[NBKT];
    __shared__ u16 bkt[EPB];
    __shared__ int2 st[EPB];     // staged packed entries (32KB)
    int tid = threadIdx.x;

    if ((int)blockIdx.x >= npb) {
        int i = ((int)blockIdx.x - npb) * 256 + tid;
        if (i < NT * D) {
            int row = i >> 7;
            int col = i & (D - 1);
            float eff = effect[row];
            float causal = (eff != 0.f) ? 1.f : 0.f;
            float zero = (eff == 0.f) ? 1.f : 0.f;
            float rmtd = bern_td[row] * zero;
            float rmtt = bern_tt[row] * zero;
            float pc = Pc[i];
            float pn = Pn[i];
            wtd16[i] = f2b(P_td[i] + b_td[col] + causal * pc - rmtd * pn);
            wtt16[i] = f2b(P_tt[i] + b_tt[col] + causal * pc - rmtt * pn);
        }
        return;
    }

    for (int i = tid; i < NBKT; i += 256) hist[i] = 0;
    __syncthreads();
    int base_e = blockIdx.x * EPB;
    for (int r = 0; r < EPB / 256; ++r) {
        int idx = r * 256 + tid;
        int e = base_e + idx;
        if (e < Etot) {
            const int *srcp, *dstp; const float* wp; int le, seg;
            resolve_rel(R, e, srcp, dstp, wp, le, seg);
            int g = seg + dstp[le];
            bkt[idx] = (u16)(g >> 7);
            st[idx] = make_int2(srcp[le] | ((g & 127) << 15),
                                __float_as_int(wp[le]));
            atomicAdd(&hist[g >> 7], 1);
        } else {
            bkt[idx] = 0xFFFF;
        }
    }
    __syncthreads();
    for (int i = tid; i < NBKT; i += 256)
        baseL[i] = hist[i] ? atomicAdd(&bucket_cursor[i], hist[i]) : 0;
    __syncthreads();
    for (int i = tid; i < NBKT; i += 256) hist[i] = 0;
    __syncthreads();
    for (int r = 0; r < EPB / 256; ++r) {
        int idx = r * 256 + tid;
        int b = bkt[idx];
        if (b != 0xFFFF) {
            int rk = atomicAdd(&hist[b], 1);
            edataA[baseL[b] + rk] = st[idx];
        }
    }
}

// ---------------------------------------------------------------------------
// B: one block (1024 threads) per bucket. LDS histogram over 128 slots ->
// scan -> COMPACT into edataB via one global atomic (gcur). Emits offsets +
// degf + edges in CSR order.
// ---------------------------------------------------------------------------
__global__ __launch_bounds__(1024) void bucket_csr_kernel(
    const int* __restrict__ bucket_base, const int* __restrict__ bucket_cursor,
    const int2* __restrict__ edataA, int2* __restrict__ edataB,
    int* __restrict__ offsets, float* __restrict__ degf, int* __restrict__ gcur)
{
    int k = blockIdx.x;
    int bstart = bucket_base[k], bend = bucket_cursor[k];
    int nk = bend - bstart;
    __shared__ int h2[BWS];
    __shared__ int exc[BWS];
    __shared__ int cbase;
    int tid = threadIdx.x;
    if (tid == 0) cbase = atomicAdd(gcur, nk);   // compacted output base
    if (tid < BWS) h2[tid] = 0;
    __syncthreads();
    for (int i = bstart + tid; i < bend; i += 1024) {
        int dloc = (edataA[i].x >> 15) & 127;
        atomicAdd(&h2[dloc], 1);
    }
    __syncthreads();
    if (tid < BWS) exc[tid] = h2[tid];
    __syncthreads();
    for (int off = 1; off < BWS; off <<= 1) {
        int t = 0;
        if (tid < BWS && tid >= off) t = exc[tid - off];
        __syncthreads();
        if (tid < BWS) exc[tid] += t;
        __syncthreads();
    }
    if (tid < BWS) exc[tid] -= h2[tid];   // exclusive
    __syncthreads();
    int slot0 = k * BWS;
    if (tid < BWS && slot0 + tid < NSLOT) {
        offsets[slot0 + tid] = cbase + exc[tid];
        degf[slot0 + tid] = (float)h2[tid];
    }
    __syncthreads();
    if (tid < BWS) h2[tid] = 0;
    __syncthreads();
    for (int i = bstart + tid; i < bend; i += 1024) {
        int2 e = edataA[i];
        int dloc = (e.x >> 15) & 127;
        int rk = atomicAdd(&h2[dloc], 1);
        edataB[cbase + exc[dloc] + rk] = e;
    }
}

// ---------------------------------------------------------------------------
// Segmented reduction (one wave per dst slot). Gather bf16, accumulate fp32,
// 16-edge main loop (8 gathers in flight per 32-lane half). S stored bf16.
// ---------------------------------------------------------------------------
__device__ __forceinline__ void reduce_one(
    const u16* __restrict__ Xb, const int* __restrict__ offsets,
    const float* __restrict__ degf, const int2* __restrict__ edata, int slot,
    int lane, u16* __restrict__ Sb, float* __restrict__ wsumf)
{
    int start = offsets[slot];
    int end = start + (int)degf[slot];
    int half = lane >> 5;
    int q = (lane & 31) * 4;   // element offset within row (4 per lane)
    float4 acc = make_float4(0.f, 0.f, 0.f, 0.f);
    float wacc = 0.f;
    int j = start;
    for (; j + 16 <= end; j += 16) {       // 8 gathers in flight per lane
        int2 ee[8];
        ushort4 vv[8];
#pragma unroll
        for (int t = 0; t < 8; ++t) ee[t] = edata[j + 2 * t + half];
#pragma unroll
        for (int t = 0; t < 8; ++t)
            vv[t] = *(const ushort4*)(Xb + (size_t)(ee[t].x & 0x7FFF) * D + q);
#pragma unroll
        for (int t = 0; t < 8; ++t) {
            float w = __int_as_float(ee[t].y);
            acc.x = fmaf(w, b2f(vv[t].x), acc.x);
            acc.y = fmaf(w, b2f(vv[t].y), acc.y);
            acc.z = fmaf(w, b2f(vv[t].z), acc.z);
            acc.w = fmaf(w, b2f(vv[t].w), acc.w);
            wacc += w;
        }
    }
    if (j + 8 <= end) {
        int2 ee[4];
        ushort4 vv[4];
#pragma unroll
        for (int t = 0; t < 4; ++t) ee[t] = edata[j + 2 * t + half];
#pragma unroll
        for (int t = 0; t < 4; ++t)
            vv[t] = *(const ushort4*)(Xb + (size_t)(ee[t].x & 0x7FFF) * D + q);
#pragma unroll
        for (int t = 0; t < 4; ++t) {
            float w = __int_as_float(ee[t].y);
            acc.x = fmaf(w, b2f(vv[t].x), acc.x);
            acc.y = fmaf(w, b2f(vv[t].y), acc.y);
            acc.z = fmaf(w, b2f(vv[t].z), acc.z);
            acc.w = fmaf(w, b2f(vv[t].w), acc.w);
            wacc += w;
        }
        j += 8;
    }
    if (j + 4 <= end) {
        int2 ea = edata[j + half];
        int2 eb = edata[j + 2 + half];
        ushort4 va = *(const ushort4*)(Xb + (size_t)(ea.x & 0x7FFF) * D + q);
        ushort4 vb = *(const ushort4*)(Xb + (size_t)(eb.x & 0x7FFF) * D + q);
        float wa = __int_as_float(ea.y);
        float wb = __int_as_float(eb.y);
        acc.x = fmaf(wa, b2f(va.x), acc.x); acc.y = fmaf(wa, b2f(va.y), acc.y);
        acc.z = fmaf(wa, b2f(va.z), acc.z); acc.w = fmaf(wa, b2f(va.w), acc.w);
        acc.x = fmaf(wb, b2f(vb.x), acc.x); acc.y = fmaf(wb, b2f(vb.y), acc.y);
        acc.z = fmaf(wb, b2f(vb.z), acc.z); acc.w = fmaf(wb, b2f(vb.w), acc.w);
        wacc += wa + wb;
        j += 4;
    }
    for (; j < end; j += 2) {
        int jj = j + half;
        int2 e = edata[jj < end ? jj : (end - 1)];
        float w = (jj < end) ? __int_as_float(e.y) : 0.f;
        ushort4 v = *(const ushort4*)(Xb + (size_t)(e.x & 0x7FFF) * D + q);
        acc.x = fmaf(w, b2f(v.x), acc.x); acc.y = fmaf(w, b2f(v.y), acc.y);
        acc.z = fmaf(w, b2f(v.z), acc.z); acc.w = fmaf(w, b2f(v.w), acc.w);
        wacc += w;
    }
    acc.x += __shfl_xor(acc.x, 32);
    acc.y += __shfl_xor(acc.y, 32);
    acc.z += __shfl_xor(acc.z, 32);
    acc.w += __shfl_xor(acc.w, 32);
    wacc  += __shfl_xor(wacc, 32);
    if (half == 0) {
        ushort4 o;
        o.x = f2b(acc.x); o.y = f2b(acc.y); o.z = f2b(acc.z); o.w = f2b(acc.w);
        *(ushort4*)(Sb + (size_t)slot * D + q) = o;
    }
    if (lane == 0 && wsumf) wsumf[slot] = wacc;
}

__global__ __launch_bounds__(256) void reduce_kernel(
    const u16* __restrict__ Xb, const int* __restrict__ offsets,
    const float* __restrict__ degf, const int2* __restrict__ edata,
    int slot0, int nslots, u16* __restrict__ Sb, float* __restrict__ wsumf)
{
    int rel = blockIdx.x * 4 + (threadIdx.x >> 6);
    if (rel >= nslots) return;
    reduce_one(Xb, offsets, degf, edata, slot0 + rel, threadIdx.x & 63, Sb, wsumf);
}

__global__ __launch_bounds__(256) void reduce_p2_kernel(
    const u16* __restrict__ hw16, const u16* __restrict__ wtt16,
    const u16* __restrict__ wtd16, const int* __restrict__ offsets,
    const float* __restrict__ degf, const int2* __restrict__ edata,
    u16* __restrict__ Sb, float* __restrict__ wsumf)
{
    int rel = blockIdx.x * 4 + (threadIdx.x >> 6);
    if (rel >= NP2) return;
    const u16* X;
    if (rel < NT)                 X = hw16;   // wt
    else if (rel < 2 * NT)        X = wtt16;  // tt
    else if (rel < 2 * NT + NDOC) X = hw16;   // wd
    else                          X = wtd16;  // td
    reduce_one(X, offsets, degf, edata, SEG_WT + rel, threadIdx.x & 63, Sb, wsumf);
}

// ---------------------------------------------------------------------------
// MFMA mm over bf16 S rows: Y = (S@W + wsum*bias)/deg [+ T/degT], optional
// bf16 mirror Yb. Block = 4 waves x 16 rows.
// ---------------------------------------------------------------------------
__device__ __forceinline__ void mfma_mm_body(
    const u16* __restrict__ Xb, const float* __restrict__ Wg,
    const float* __restrict__ deg, const float* __restrict__ wsum,
    const float* __restrict__ bias,
    const u16* __restrict__ T, const float* __restrict__ degT,
    float* __restrict__ Y, u16* __restrict__ Yb, int n,
    u16* Wt, int tid, int bx)
{
    stage_wt(Wg, Wt, tid);
    __syncthreads();
    int wv = tid >> 6, lane = tid & 63;
    int lanelo = lane & 15, quad = lane >> 4;
    int rowbase = bx * 64 + wv * 16;
    f32x4 acc[8];
    mfma_tile_b16(Xb, Wt, rowbase + lanelo, n, lanelo, quad, acc);

    int rbase = rowbase + quad * 4;
#pragma unroll
    for (int r = 0; r < 4; ++r) {
        int row = rbase + r;
        if (row >= n) continue;
        float dgv = deg[row];
        float wsv = wsum ? wsum[row] : 0.f;
        float dtv = degT ? degT[row] : 0.f;
#pragma unroll
        for (int ct = 0; ct < 8; ++ct) {
            int col = ct * 16 + lanelo;
            float y = acc[ct][r];
            y = dgv > 0.f ? (y + wsv * bias[col]) / dgv : 0.f;
            if (T && dtv > 0.f) y += b2f(T[(size_t)row * D + col]) / dtv;
            Y[(size_t)row * D + col] = y;
            if (Yb) Yb[(size_t)row * D + col] = f2b(y);
        }
    }
}

__global__ __launch_bounds__(256) void mfma_mm_kernel(
    const u16* __restrict__ Xb, const float* __restrict__ Wg,
    const float* __restrict__ deg, const float* __restrict__ wsum,
    const float* __restrict__ bias,
    const u16* __restrict__ T, const float* __restrict__ degT,
    float* __restrict__ Y, u16* __restrict__ Yb, int n)
{
    __shared__ u16 Wt[D * WPITCH];
    mfma_mm_body(Xb, Wg, deg, wsum, bias, T, degT, Y, Yb, n,
                 Wt, threadIdx.x, blockIdx.x);
}

// Final projections merged: blocks [0,nb0) -> topic, [nb0,..) -> doc.
struct MMF {
    const u16* X[2]; const float* W[2]; const float* deg[2];
    const float* wsum[2]; const float* bias[2];
    const u16* T[2]; const float* degT[2];
    float* Y[2]; int n[2]; int nb0;
};
__global__ __launch_bounds__(256) void mfma_mm2_kernel(MMF p)
{
    __shared__ u16 Wt[D * WPITCH];
    int which = (int)(blockIdx.x >= (unsigned)p.nb0);
    int bx = which ? (int)blockIdx.x - p.nb0 : (int)blockIdx.x;
    mfma_mm_body(p.X[which], p.W[which], p.deg[which], p.wsum[which],
                 p.bias[which], p.T[which], p.degT[which], p.Y[which],
                 nullptr, p.n[which], Wt, threadIdx.x, bx);
}

extern "C" void kernel_launch(void* const* d_in, const int* in_sizes, int n_in,
                              void* d_out, int out_size, void* d_ws, size_t ws_size,
                              hipStream_t stream)
{
    const float* feat_word  = (const float*)d_in[0];
    const float* feat_topic = (const float*)d_in[1];
    const float* effect     = (const float*)d_in[2];
    const float* bern_td    = (const float*)d_in[3];
    const float* bern_tt    = (const float*)d_in[4];
    const int*   src_ww = (const int*)d_in[5];
    const int*   dst_ww = (const int*)d_in[6];
    const float* w_ww   = (const float*)d_in[7];
    const int*   src_wt = (const int*)d_in[8];
    const int*   dst_wt = (const int*)d_in[9];
    const float* w_wt   = (const float*)d_in[10];
    const int*   src_wd = (const int*)d_in[11];
    const int*   dst_wd = (const int*)d_in[12];
    const float* w_wd   = (const float*)d_in[13];
    const int*   src_td = (const int*)d_in[14];
    const int*   dst_td = (const int*)d_in[15];
    const float* w_td   = (const float*)d_in[16];
    const int*   src_tt = (const int*)d_in[17];
    const int*   dst_tt = (const int*)d_in[18];
    const float* w_tt   = (const float*)d_in[19];
    const float* W_ww = (const float*)d_in[20];
    const float* b_ww = (const float*)d_in[21];
    const float* W_wt = (const float*)d_in[22];
    const float* b_wt = (const float*)d_in[23];
    const float* W_wd = (const float*)d_in[24];
    const float* b_wd = (const float*)d_in[25];
    const float* W_td = (const float*)d_in[26];
    const float* b_td = (const float*)d_in[27];
    const float* W_tt = (const float*)d_in[28];
    const float* b_tt = (const float*)d_in[29];
    const float* W_causal = (const float*)d_in[30];
    const float* W_noise  = (const float*)d_in[31];

    const int E_ww = in_sizes[5];
    const int E_wt = in_sizes[8];
    const int E_wd = in_sizes[11];
    const int E_td = in_sizes[14];
    const int E_tt = in_sizes[17];
    const int E_total = E_ww + E_wt + E_wd + E_td + E_tt;
    // padded edataA capacity: sum of per-bucket caps <= 1.5*E_total + 128*NBKT
    const long long capA = (long long)(1.5 * E_total) + 128LL * NBKT + 256;

    // ---- workspace layout (4-byte units; dedicated regions, NO overlays) ----
    float* ws = (float*)d_ws;
    u16*   Sb    = (u16*)ws; ws += (long long)NSLOT * D / 2;   // bf16 agg sums
    float* degf  = ws; ws += NSLOT;
    float* wsumf = ws; ws += NSLOT;
    int*   offsets      = (int*)ws; ws += NSLOT + 1;
    int*   bucket_base  = (int*)ws; ws += NBKT + 1;
    int*   bucket_cursor= (int*)ws; ws += NBKT;
    int*   gcur         = (int*)ws; ws += 1;
    ws += ((size_t)(ws - (float*)d_ws) & 1);          // 8B align
    int2*  edataB   = (int2*)ws; ws += (long long)2 * E_total;   // compact coords
    int2*  edataA   = (int2*)ws; ws += 2 * capA;                 // padded coords
    float* P_td  = ws; ws += (long long)NT * D;
    float* P_tt  = ws; ws += (long long)NT * D;
    float* Pc    = ws; ws += (long long)NT * D;
    float* Pn    = ws; ws += (long long)NT * D;
    u16*   fw16     = (u16*)ws;  ws += (long long)NW * D / 2;   // bf16 feat_word
    u16*   hw16     = (u16*)ws;  ws += (long long)NW * D / 2;   // bf16 h_word
    u16*   wtd16    = (u16*)ws;  ws += (long long)NT * D / 2;
    u16*   wtt16    = (u16*)ws;  ws += (long long)NT * D / 2;

    float* h_word  = (float*)d_out;
    float* h_topic = h_word + (long long)NW * D;
    float* h_doc   = h_topic + (long long)NT * D;

    auto nb = [](long long n) { return (unsigned)((n + 255) / 256); };

    Rels R;
    R.r[0] = { src_ww, dst_ww, w_ww, 0, SEG_WW };
    R.r[1] = { src_wt, dst_wt, w_wt, E_ww, SEG_WT };
    R.r[2] = { src_tt, dst_tt, w_tt, E_ww + E_wt, SEG_TT };
    R.r[3] = { src_wd, dst_wd, w_wd, E_ww + E_wt + E_tt, SEG_WD };
    R.r[4] = { src_td, dst_td, w_td, E_ww + E_wt + E_tt + E_wd, SEG_TD };

    // ---- merged prep: cap_scan + f2b + 4 topic matmuls ----
    MM4 m4;
    m4.W[0] = W_td; m4.W[1] = W_tt; m4.W[2] = W_causal; m4.W[3] = W_noise;
    m4.P[0] = P_td; m4.P[1] = P_tt; m4.P[2] = Pc;       m4.P[3] = Pn;
    prep_kernel<<<1 + NF2B + 4 * NBM4, 256, 0, stream>>>(
        feat_word, fw16, feat_topic, m4,
        (float)E_ww / NW, (float)E_wt / NT, (float)E_tt / NT,
        (float)E_wd / NDOC, (float)E_td / NDOC,
        bucket_base, bucket_cursor, gcur);

    // ---- merged partition + Wh combine ----
    unsigned npb = (unsigned)((E_total + EPB - 1) / EPB);
    part_combine_kernel<<<npb + nb((long long)NT * D), 256, 0, stream>>>(
        R, E_total, bucket_cursor, edataA,
        P_td, P_tt, Pc, Pn, effect, bern_td, bern_tt, b_td, b_tt,
        wtd16, wtt16, (int)npb);

    bucket_csr_kernel<<<NBKT, 1024, 0, stream>>>(
        bucket_base, bucket_cursor, edataA, edataB, offsets, degf, gcur);

    // ---- Phase 1: ww reduce + word projection (fp32 out + bf16 mirror) ----
    reduce_kernel<<<(NW + 3) / 4, 256, 0, stream>>>(
        fw16, offsets, degf, edataB, SEG_WW, NW, Sb, wsumf);
    mfma_mm_kernel<<<(NW + 63) / 64, 256, 0, stream>>>(
        Sb + (long long)SEG_WW * D, W_ww, degf + SEG_WW, wsumf + SEG_WW, b_ww,
        nullptr, nullptr, h_word, hw16, NW);

    // ---- Phase 2: merged reduce over wt/tt/wd/td ----
    reduce_p2_kernel<<<(NP2 + 3) / 4, 256, 0, stream>>>(
        hw16, wtt16, wtd16, offsets, degf, edataB, Sb, wsumf);

    // ---- Final projections (topic + doc merged into one dispatch) ----
    MMF mf;
    mf.X[0] = Sb + (long long)SEG_WT * D;  mf.X[1] = Sb + (long long)SEG_WD * D;
    mf.W[0] = W_wt;                        mf.W[1] = W_wd;
    mf.deg[0] = degf + SEG_WT;             mf.deg[1] = degf + SEG_WD;
    mf.wsum[0] = wsumf + SEG_WT;           mf.wsum[1] = wsumf + SEG_WD;
    mf.bias[0] = b_wt;                     mf.bias[1] = b_wd;
    mf.T[0] = Sb + (long long)SEG_TT * D;  mf.T[1] = Sb + (long long)SEG_TD * D;
    mf.degT[0] = degf + SEG_TT;            mf.degT[1] = degf + SEG_TD;
    mf.Y[0] = h_topic;                     mf.Y[1] = h_doc;
    mf.n[0] = NT;                          mf.n[1] = NDOC;
    mf.nb0 = (NT + 63) / 64;
    unsigned nbf = (unsigned)((NT + 63) / 64 + (NDOC + 63) / 64);
    mfma_mm2_kernel<<<nbf, 256, 0, stream>>>(mf);

    (void)n_in; (void)in_sizes; (void)out_size; (void)ws_size;
}